// Round 6
// baseline (199.001 us; speedup 1.0000x reference)
//
#include <hip/hip_runtime.h>
#include <hip/hip_bf16.h>
#include <cstdint>

#define NN 2048
#define NH 4
#define NW 64   // mask words per row

typedef __attribute__((ext_vector_type(8))) short bf16x8;
typedef __attribute__((ext_vector_type(4))) float f32x4;
typedef __attribute__((ext_vector_type(4))) unsigned short u16x4;

__device__ __forceinline__ float lrelu(float s) { return s > 0.f ? s : 0.2f * s; }

__device__ __forceinline__ unsigned pk2(float lo, float hi) {
  __hip_bfloat162 h2 = __float22bfloat162_rn(make_float2(lo, hi));
  union { __hip_bfloat162 h; unsigned u; } c; c.h = h2; return c.u;
}
__device__ __forceinline__ short f2bf1(float f) {
  __hip_bfloat16 h = __float2bfloat16(f);
  union { __hip_bfloat16 h; unsigned short u; } c; c.h = h; return (short)c.u;
}
__device__ __forceinline__ bf16x8 cvt8(f32x4 v0, f32x4 v1) {
  union { unsigned u[4]; bf16x8 v; } r;
  r.u[0] = pk2(v0[0], v0[1]); r.u[1] = pk2(v0[2], v0[3]);
  r.u[2] = pk2(v1[0], v1[1]); r.u[3] = pk2(v1[2], v1[3]);
  return r.v;
}

// Fragment layout for Wh^T (per (b,h) slab of F feats x 2048 nodes):
// short index = (kb*FT + ft)*512 + (feat&15)*8 + gd*128 + e  with node = kb*32+8*gd+e
// -> k-attn lane `lane` loads 16B at frag_base + (kb*FT+ft)*512 + lane*8
//    holding feat = ft*16 + (lane&15), nodes = kb*32 + (lane>>4)*8 .. +7 (B-frag order)

// ---------- kA: blocks [0,512): proj1 (launch first); [512,4608): ballot-pack --
__global__ __launch_bounds__(256) void kA(
    const int* __restrict__ adj, unsigned* __restrict__ mb,
    const float* __restrict__ x, const float* __restrict__ W1,
    const float* __restrict__ a1, unsigned short* __restrict__ wht1,
    float* __restrict__ ssrc1, float* __restrict__ G1g, float* __restrict__ G2g,
    unsigned* __restrict__ mx1u) {
  if (blockIdx.x >= 512) {
    // ballot pack: wave processes 4 x 256 consecutive ints, no cross-lane data ops
    int pb = blockIdx.x - 512;                     // 0..4095
    int lane = threadIdx.x & 63;
    size_t base = ((size_t)pb * 4 + (threadIdx.x >> 6)) * 1024;
#pragma unroll
    for (int it = 0; it < 4; ++it) {
      size_t b0 = base + it * 256;
      int v0 = adj[b0 + lane];
      int v1 = adj[b0 + 64 + lane];
      int v2 = adj[b0 + 128 + lane];
      int v3 = adj[b0 + 192 + lane];
      unsigned long long m0 = __ballot(v0 != 0);   // bits = elements b0+0..63
      unsigned long long m1 = __ballot(v1 != 0);
      unsigned long long m2 = __ballot(v2 != 0);
      unsigned long long m3 = __ballot(v3 != 0);
      if (lane < 8) {
        unsigned long long mm = (lane < 4) ? ((lane < 2) ? m0 : m1)
                                           : ((lane < 6) ? m2 : m3);
        mb[b0 / 32 + lane] = (lane & 1) ? (unsigned)(mm >> 32) : (unsigned)mm;
      }
    }
    return;
  }
  int blk = blockIdx.x;                // 0..511 proj1, 16 rows each
  int rowg = blk * 16;
  int b = rowg >> 11, rloc = rowg & (NN - 1);
  int tid = threadIdx.x, lane = tid & 63, h = tid >> 6;
  int cl = lane & 15, g = lane >> 4;

  const float* xr = x + (size_t)(rowg + cl) * 64 + 8 * g;
  bf16x8 af[2];
#pragma unroll
  for (int ks = 0; ks < 2; ++ks)
    af[ks] = cvt8(*(const f32x4*)(xr + ks * 32), *(const f32x4*)(xr + ks * 32 + 4));

  f32x4 zero = {0.f, 0.f, 0.f, 0.f};
  f32x4 acc[4] = {zero, zero, zero, zero};
#pragma unroll
  for (int ft = 0; ft < 4; ++ft) {
    const float* wr = W1 + (size_t)(h * 64 + ft * 16 + cl) * 64 + 8 * g;
#pragma unroll
    for (int ks = 0; ks < 2; ++ks) {
      bf16x8 bfr = cvt8(*(const f32x4*)(wr + ks * 32), *(const f32x4*)(wr + ks * 32 + 4));
      acc[ft] = __builtin_amdgcn_mfma_f32_16x16x32_bf16(af[ks], bfr, acc[ft], 0, 0, 0);
    }
  }
  // fragment-layout store: node J = rloc+4g+r, feat F = ft*16+cl
  unsigned short* bhb = wht1 + (size_t)(b * NH + h) * 64 * NN;
  int kb = rloc >> 5;
  int gd = ((rloc >> 3) & 2) + (g >> 1);
  int e0 = 4 * (g & 1);
  float ps[4] = {0.f, 0.f, 0.f, 0.f}, pd[4] = {0.f, 0.f, 0.f, 0.f};
#pragma unroll
  for (int ft = 0; ft < 4; ++ft) {
    float as = a1[h * 128 + ft * 16 + cl];
    float ad = a1[h * 128 + 64 + ft * 16 + cl];
    u16x4 w4;
#pragma unroll
    for (int r = 0; r < 4; ++r) {
      float v = acc[ft][r];
      w4[r] = (unsigned short)f2bf1(v);
      ps[r] += v * as; pd[r] += v * ad;
    }
    *(u16x4*)(bhb + (size_t)(kb * 4 + ft) * 512 + cl * 8 + gd * 128 + e0) = w4;
  }
  float gm = 0.f;
#pragma unroll
  for (int r = 0; r < 4; ++r) {
    float s = ps[r], d = pd[r];
    s += __shfl_xor(s, 1); s += __shfl_xor(s, 2); s += __shfl_xor(s, 4); s += __shfl_xor(s, 8);
    d += __shfl_xor(d, 1); d += __shfl_xor(d, 2); d += __shfl_xor(d, 4); d += __shfl_xor(d, 8);
    float g1v = __expf(d);
    gm = fmaxf(gm, g1v);
    if (cl == 0) {
      int idx = (b * NH + h) * NN + rloc + 4 * g + r;
      ssrc1[idx] = s;
      G1g[idx] = g1v;
      G2g[idx] = __expf(0.2f * d);
    }
  }
  gm = fmaxf(gm, __shfl_xor(gm, 16));
  gm = fmaxf(gm, __shfl_xor(gm, 32));
  if (lane == 0) atomicMax(&mx1u[b * NH + h], __float_as_uint(gm));
}

// ---------- k2: layer-1 attention. bid=[tile(5)][bh(4)] -> XCD pinned per (b,h)
// block = 64 rows, 8 waves = 4 row-tiles x 2 j-halves; 32-iter loop + prefetch
__global__ __launch_bounds__(512) void k2_attn1(
    const unsigned short* __restrict__ wht1, const float* __restrict__ ssrc1,
    const float* __restrict__ G1g, const float* __restrict__ G2g,
    const unsigned* __restrict__ mb, const unsigned* __restrict__ mx1u,
    float* __restrict__ hout) {
  // phase 1: sdm[64][65] 16640 B | sG1 8 KB | sG2 8 KB = 33024 B
  // phase 2 (overlay): cmb[4][16][68] 17408 B + sden[4][16] 256 B
  __shared__ __align__(16) char smem[33280];
  unsigned (*sdm)[65] = (unsigned(*)[65])smem;
  float* sG1 = (float*)(smem + 16640);
  float* sG2 = (float*)(smem + 16640 + 8192);
  float (*cmb)[16][68] = (float(*)[16][68])smem;
  float (*sden)[16] = (float(*)[16])(smem + 17408);

  int bid = blockIdx.x;                // 512 = [tile(5 bits hi)][bh(4 bits lo)]
  int bh = bid & 15, tile = bid >> 4;  // bid%8 = bh%8 -> same XCD per (b,h)
  int b = bh >> 2, h = bh & 3;
  int rowblk = tile << 6;
  int t = threadIdx.x, lane = t & 63, w = t >> 6;
  int wloc = w & 3, jh = w >> 2;
  int cl = lane & 15, g = lane >> 4, g8 = g * 8;

  { // stage 64 rows x 64 mask words (8 words per thread)
    int row = t >> 3, c = (t & 7) * 8;
    const unsigned* mrow = mb + (size_t)(b * NN + rowblk + row) * NW + c;
    uint4 v0 = *(const uint4*)(mrow);
    uint4 v1 = *(const uint4*)(mrow + 4);
    sdm[row][c + 0] = v0.x; sdm[row][c + 1] = v0.y;
    sdm[row][c + 2] = v0.z; sdm[row][c + 3] = v0.w;
    sdm[row][c + 4] = v1.x; sdm[row][c + 5] = v1.y;
    sdm[row][c + 6] = v1.z; sdm[row][c + 7] = v1.w;
  }
  { // stage G1/G2 (2048 floats each)
    const f32x4* g1p = (const f32x4*)(G1g + (size_t)(b * NH + h) * NN);
    const f32x4* g2p = (const f32x4*)(G2g + (size_t)(b * NH + h) * NN);
    ((f32x4*)sG1)[t] = g1p[t];
    ((f32x4*)sG2)[t] = g2p[t];
  }
  float logMx = __logf(__uint_as_float(mx1u[b * NH + h]));
  int rowW = rowblk + wloc * 16;
  float s = ssrc1[(size_t)(b * NH + h) * NN + rowW + cl];
  float m = lrelu(s + logMx);          // valid per-row softmax shift (upper bound)
  float F1 = __expf(s - m), F2 = __expf(0.2f * s - m);
  __syncthreads();

  short onev = (cl == 0) ? (short)0x3F80 : (short)0;
  bf16x8 ones = {onev, onev, onev, onev, onev, onev, onev, onev};
  f32x4 zero = {0.f, 0.f, 0.f, 0.f};
  f32x4 acc[4] = {zero, zero, zero, zero};
  f32x4 acc1 = zero;                   // denominator via ones column
  const unsigned short* fbase = wht1 + (size_t)(b * NH + h) * 64 * NN + lane * 8;
  int rloc = wloc * 16 + cl;
  int kb0 = jh * 32;

  bf16x8 curf[4], nxtf[4];
#pragma unroll
  for (int ft = 0; ft < 4; ++ft)
    curf[ft] = *(const bf16x8*)(fbase + (size_t)(kb0 * 4 + ft) * 512);

  for (int i = 0; i < 32; ++i) {
    int kb = kb0 + i;
    if (i < 31) {                      // prefetch next iteration's fragments
#pragma unroll
      for (int ft = 0; ft < 4; ++ft)
        nxtf[ft] = *(const bf16x8*)(fbase + (size_t)((kb + 1) * 4 + ft) * 512);
    }
    unsigned by = (sdm[rloc][kb] >> g8) & 0xFFu;
    int j0 = kb * 32 + g8;
    f32x4 g1a = *(const f32x4*)(sG1 + j0);
    f32x4 g1b = *(const f32x4*)(sG1 + j0 + 4);
    f32x4 g2a = *(const f32x4*)(sG2 + j0);
    f32x4 g2b = *(const f32x4*)(sG2 + j0 + 4);
    float wv[8];
#pragma unroll
    for (int e = 0; e < 8; ++e) {
      float g1 = (e < 4) ? g1a[e] : g1b[e - 4];
      float g2 = (e < 4) ? g2a[e] : g2b[e - 4];
      float v = fmaxf(F1 * g1, F2 * g2);   // exp(lrelu(s+t)-m), branch-free
      wv[e] = ((by >> e) & 1u) ? v : 0.f;
    }
    union { unsigned u[4]; bf16x8 v; } pa;
    pa.u[0] = pk2(wv[0], wv[1]); pa.u[1] = pk2(wv[2], wv[3]);
    pa.u[2] = pk2(wv[4], wv[5]); pa.u[3] = pk2(wv[6], wv[7]);
#pragma unroll
    for (int ft = 0; ft < 4; ++ft)
      acc[ft] = __builtin_amdgcn_mfma_f32_16x16x32_bf16(pa.v, curf[ft], acc[ft], 0, 0, 0);
    acc1 = __builtin_amdgcn_mfma_f32_16x16x32_bf16(pa.v, ones, acc1, 0, 0, 0);
#pragma unroll
    for (int ft = 0; ft < 4; ++ft) curf[ft] = nxtf[ft];
  }
  __syncthreads();                     // all LDS reads done; overlay safe
  if (jh == 1) {
#pragma unroll
    for (int ft = 0; ft < 4; ++ft)
#pragma unroll
      for (int r = 0; r < 4; ++r)
        cmb[wloc][4 * g + r][ft * 16 + cl] = acc[ft][r];
    if (cl == 0) {
#pragma unroll
      for (int r = 0; r < 4; ++r) sden[wloc][4 * g + r] = acc1[r];
    }
  }
  __syncthreads();
  if (jh == 0) {
#pragma unroll
    for (int r = 0; r < 4; ++r) {
      int rowm = 4 * g + r;
      float dself = __shfl(acc1[r], lane & 48);   // denom col 0 lives at cl==0
      float inv = 1.f / (dself + sden[wloc][rowm]);
      float* dst = hout + (size_t)(b * NN + rowW + rowm) * 256 + h * 64;
#pragma unroll
      for (int ft = 0; ft < 4; ++ft) {
        float v = (acc[ft][r] + cmb[wloc][rowm][ft * 16 + cl]) * inv;
        v = v > 0.f ? v : (__expf(v) - 1.f);      // ELU
        dst[ft * 16 + cl] = v;
      }
    }
  }
}

// ---------- k3: Wh2 = h @ W2^T via MFMA split-K; frag-layout store + scores ----
__global__ __launch_bounds__(256) void k3_proj2(
    const float* __restrict__ hin, const float* __restrict__ W2,
    const float* __restrict__ a2, unsigned short* __restrict__ wh2t,
    float* __restrict__ ssrc2, float* __restrict__ G1o, float* __restrict__ G2o,
    unsigned* __restrict__ mx2u) {
  __shared__ float cmb[4][16][33];
  int blk = blockIdx.x;                 // 512: 16 rows each
  int b = blk >> 7, rowbase = (blk & 127) << 4;
  int t = threadIdx.x, lane = t & 63, w = t >> 6;
  int cl = lane & 15, g = lane >> 4;
  int k0 = w * 64;                      // K split across 4 waves

  const float* hr = hin + (size_t)(b * NN + rowbase + cl) * 256 + k0 + 8 * g;
  bf16x8 af[2];
#pragma unroll
  for (int ks = 0; ks < 2; ++ks)
    af[ks] = cvt8(*(const f32x4*)(hr + ks * 32), *(const f32x4*)(hr + ks * 32 + 4));

  f32x4 zero = {0.f, 0.f, 0.f, 0.f};
  f32x4 acc[2] = {zero, zero};
#pragma unroll
  for (int ft = 0; ft < 2; ++ft) {
    const float* wr = W2 + (size_t)(ft * 16 + cl) * 256 + k0 + 8 * g;
#pragma unroll
    for (int ks = 0; ks < 2; ++ks) {
      bf16x8 bfr = cvt8(*(const f32x4*)(wr + ks * 32), *(const f32x4*)(wr + ks * 32 + 4));
      acc[ft] = __builtin_amdgcn_mfma_f32_16x16x32_bf16(af[ks], bfr, acc[ft], 0, 0, 0);
    }
  }
#pragma unroll
  for (int ft = 0; ft < 2; ++ft)
#pragma unroll
    for (int r = 0; r < 4; ++r)
      cmb[w][4 * g + r][ft * 16 + cl] = acc[ft][r];
  __syncthreads();

  int row = t >> 4, c0 = t & 15;
  float v0 = cmb[0][row][c0] + cmb[1][row][c0] + cmb[2][row][c0] + cmb[3][row][c0];
  float v1 = cmb[0][row][c0 + 16] + cmb[1][row][c0 + 16] + cmb[2][row][c0 + 16] + cmb[3][row][c0 + 16];
  float ps = v0 * a2[c0] + v1 * a2[c0 + 16];
  float pd = v0 * a2[32 + c0] + v1 * a2[32 + c0 + 16];
  ps += __shfl_xor(ps, 1); ps += __shfl_xor(ps, 2); ps += __shfl_xor(ps, 4); ps += __shfl_xor(ps, 8);
  pd += __shfl_xor(pd, 1); pd += __shfl_xor(pd, 2); pd += __shfl_xor(pd, 4); pd += __shfl_xor(pd, 8);
  if (c0 == 0) {
    int idx = b * NN + rowbase + row;
    ssrc2[idx] = ps;
    float g1v = __expf(pd);
    G1o[idx] = g1v;
    G2o[idx] = __expf(0.2f * pd);
    atomicMax(&mx2u[b], __float_as_uint(g1v));
  }
  cmb[0][row][c0] = v0;
  cmb[0][row][c0 + 16] = v1;
  __syncthreads();
  // fragment-layout bf16 store: feat = col, nodes J = rowbase + 2*rg + {0,1}
  int col = t >> 3, rg = t & 7;
  unsigned pk = pk2(cmb[0][2 * rg][col], cmb[0][2 * rg + 1][col]);
  int kb2 = rowbase >> 5;
  int gd = ((rowbase >> 3) & 2) + (rg >> 2);
  size_t off = (size_t)(kb2 * 2 + (col >> 4)) * 512 + (col & 15) * 8 + gd * 128 + 2 * (rg & 3);
  *(unsigned*)(wh2t + (size_t)b * 32 * NN + off) = pk;
}

// ---------- k4: layer-2 attention. block = 16 rows; 8 waves = 8 j-chunks -------
__global__ __launch_bounds__(512) void k4_attn2(
    const unsigned short* __restrict__ wh2t, const float* __restrict__ ssrc2,
    const float* __restrict__ G1o, const float* __restrict__ G2o,
    const unsigned* __restrict__ mb, const unsigned* __restrict__ mx2u,
    float* __restrict__ outp) {
  __shared__ unsigned sdm[16][65];                 // 4.2 KB
  __shared__ __align__(16) float sG1[NN], sG2[NN]; // 16 KB
  __shared__ float pacc[16 * 33];                  // 2.1 KB
  __shared__ float pden[16];
  int blk = blockIdx.x;                // 512: 16 rows each
  int b = blk >> 7, rowbase = (blk & 127) << 4;
  int t = threadIdx.x, lane = t & 63, w = t >> 6;
  int cl = lane & 15, g = lane >> 4, g8 = g * 8;
  { // stage 16 rows x 64 words (2 per thread)
    int row = t >> 5, c = (t & 31) * 2;
    uint2 v = *(const uint2*)(mb + (size_t)(b * NN + rowbase + row) * NW + c);
    sdm[row][c + 0] = v.x; sdm[row][c + 1] = v.y;
  }
  {
    const f32x4* g1p = (const f32x4*)(G1o + (size_t)b * NN);
    const f32x4* g2p = (const f32x4*)(G2o + (size_t)b * NN);
    ((f32x4*)sG1)[t] = g1p[t];
    ((f32x4*)sG2)[t] = g2p[t];
  }
  for (int i = t; i < 16 * 33; i += 512) pacc[i] = 0.f;
  if (t < 16) pden[t] = 0.f;

  float logMx = __logf(__uint_as_float(mx2u[b]));
  float s = ssrc2[b * NN + rowbase + cl];
  float m = lrelu(s + logMx);
  float F1 = __expf(s - m), F2 = __expf(0.2f * s - m);
  __syncthreads();

  short onev = (cl == 0) ? (short)0x3F80 : (short)0;
  bf16x8 ones = {onev, onev, onev, onev, onev, onev, onev, onev};
  f32x4 zero = {0.f, 0.f, 0.f, 0.f};
  f32x4 acc[2] = {zero, zero};
  f32x4 acc1 = zero;
  const unsigned short* fbase = wh2t + (size_t)b * 32 * NN + lane * 8;
  int kb0 = w * 8;

  bf16x8 curf[2], nxtf[2];
#pragma unroll
  for (int ft = 0; ft < 2; ++ft)
    curf[ft] = *(const bf16x8*)(fbase + (size_t)(kb0 * 2 + ft) * 512);

  for (int i = 0; i < 8; ++i) {
    int kb = kb0 + i;
    if (i < 7) {
#pragma unroll
      for (int ft = 0; ft < 2; ++ft)
        nxtf[ft] = *(const bf16x8*)(fbase + (size_t)((kb + 1) * 2 + ft) * 512);
    }
    unsigned by = (sdm[cl][kb] >> g8) & 0xFFu;
    int j0 = kb * 32 + g8;
    f32x4 g1a = *(const f32x4*)(sG1 + j0);
    f32x4 g1b = *(const f32x4*)(sG1 + j0 + 4);
    f32x4 g2a = *(const f32x4*)(sG2 + j0);
    f32x4 g2b = *(const f32x4*)(sG2 + j0 + 4);
    float wv[8];
#pragma unroll
    for (int e = 0; e < 8; ++e) {
      float g1 = (e < 4) ? g1a[e] : g1b[e - 4];
      float g2 = (e < 4) ? g2a[e] : g2b[e - 4];
      float v = fmaxf(F1 * g1, F2 * g2);
      wv[e] = ((by >> e) & 1u) ? v : 0.f;
    }
    union { unsigned u[4]; bf16x8 v; } pa;
    pa.u[0] = pk2(wv[0], wv[1]); pa.u[1] = pk2(wv[2], wv[3]);
    pa.u[2] = pk2(wv[4], wv[5]); pa.u[3] = pk2(wv[6], wv[7]);
#pragma unroll
    for (int ft = 0; ft < 2; ++ft)
      acc[ft] = __builtin_amdgcn_mfma_f32_16x16x32_bf16(pa.v, curf[ft], acc[ft], 0, 0, 0);
    acc1 = __builtin_amdgcn_mfma_f32_16x16x32_bf16(pa.v, ones, acc1, 0, 0, 0);
#pragma unroll
    for (int ft = 0; ft < 2; ++ft) curf[ft] = nxtf[ft];
  }
#pragma unroll
  for (int ft = 0; ft < 2; ++ft)
#pragma unroll
    for (int r = 0; r < 4; ++r)
      atomicAdd(&pacc[(4 * g + r) * 33 + ft * 16 + cl], acc[ft][r]);
  if (cl == 0) {
#pragma unroll
    for (int r = 0; r < 4; ++r) atomicAdd(&pden[4 * g + r], acc1[r]);
  }
  __syncthreads();
  { // epilogue: 512 threads x 1 value
    int row = t >> 5, f = t & 31;
    outp[(size_t)(b * NN + rowbase + row) * 32 + f] = pacc[row * 33 + f] / pden[row];
  }
}

extern "C" void kernel_launch(void* const* d_in, const int* in_sizes, int n_in,
                              void* d_out, int out_size, void* d_ws, size_t ws_size,
                              hipStream_t stream) {
  (void)in_sizes; (void)n_in; (void)out_size; (void)ws_size;
  const float* x   = (const float*)d_in[0];
  const int*   adj = (const int*)d_in[1];
  const float* W1  = (const float*)d_in[2];
  const float* a1  = (const float*)d_in[3];
  const float* W2  = (const float*)d_in[4];
  const float* a2  = (const float*)d_in[5];
  float* outp = (float*)d_out;
  char* ws = (char*)d_ws;

  unsigned*       mbits = (unsigned*)(ws);                                   // 2 MB
  unsigned short* wht1  = (unsigned short*)(ws + (size_t)(2u << 20));        // 4 MB
  float*          ssrc1 = (float*)(ws + (size_t)(6u << 20));                 // 128 KB
  float*          G1g   = (float*)(ws + (size_t)(6u << 20) + (128u << 10));  // 128 KB
  float*          G2g   = (float*)(ws + (size_t)(6u << 20) + (256u << 10));  // 128 KB
  float*          hbuf  = (float*)(ws + (size_t)(6u << 20) + (512u << 10));  // 8 MB
  unsigned short* wh2t  = (unsigned short*)(ws + (size_t)(14u << 20) + (512u << 10)); // 512 KB
  float*          ssrc2 = (float*)(ws + (size_t)(15u << 20));                // 32 KB
  float*          G1o   = (float*)(ws + (size_t)(15u << 20) + (32u << 10));  // 32 KB
  float*          G2o   = (float*)(ws + (size_t)(15u << 20) + (64u << 10));  // 32 KB
  unsigned*       mx1u  = (unsigned*)(ws + (size_t)(15u << 20) + (96u << 10)); // 64 B
  unsigned*       mx2u  = mx1u + 16;                                           // 16 B

  hipMemsetAsync(mx1u, 0, 128, stream);
  kA      <<<4608, 256, 0, stream>>>(adj, mbits, x, W1, a1, wht1, ssrc1, G1g, G2g, mx1u);
  k2_attn1<<<512,  512, 0, stream>>>(wht1, ssrc1, G1g, G2g, mbits, mx1u, hbuf);
  k3_proj2<<<512,  256, 0, stream>>>(hbuf, W2, a2, wh2t, ssrc2, G1o, G2o, mx2u);
  k4_attn2<<<512,  512, 0, stream>>>(wh2t, ssrc2, G1o, G2o, mbits, mx2u, outp);
}

// Round 7
// 168.296 us; speedup vs baseline: 1.1824x; 1.1824x over previous
//
#include <hip/hip_runtime.h>
#include <hip/hip_bf16.h>
#include <cstdint>

#define NN 2048
#define NH 4
#define NW 64   // mask words per row

typedef __attribute__((ext_vector_type(8))) short bf16x8;
typedef __attribute__((ext_vector_type(4))) float f32x4;
typedef __attribute__((ext_vector_type(4))) int i32x4;
typedef __attribute__((ext_vector_type(4))) unsigned short u16x4;

__device__ __forceinline__ float lrelu(float s) { return s > 0.f ? s : 0.2f * s; }

__device__ __forceinline__ unsigned pk2(float lo, float hi) {
  __hip_bfloat162 h2 = __float22bfloat162_rn(make_float2(lo, hi));
  union { __hip_bfloat162 h; unsigned u; } c; c.h = h2; return c.u;
}
__device__ __forceinline__ short f2bf1(float f) {
  __hip_bfloat16 h = __float2bfloat16(f);
  union { __hip_bfloat16 h; unsigned short u; } c; c.h = h; return (short)c.u;
}
__device__ __forceinline__ bf16x8 cvt8(f32x4 v0, f32x4 v1) {
  union { unsigned u[4]; bf16x8 v; } r;
  r.u[0] = pk2(v0[0], v0[1]); r.u[1] = pk2(v0[2], v0[3]);
  r.u[2] = pk2(v1[0], v1[1]); r.u[3] = pk2(v1[2], v1[3]);
  return r.v;
}

// Fragment layout for Wh^T (per (b,h) slab of F feats x 2048 nodes):
// short index = (kb*FT + ft)*512 + (feat&15)*8 + gd*128 + e  with node = kb*32+8*gd+e
// -> k-attn lane `lane` loads 16B at frag_base + (kb*FT+ft)*512 + lane*8
//    holding feat = ft*16 + (lane&15), nodes = kb*32 + (lane>>4)*8 .. +7 (B-frag order)

// ---------- kA: blocks [0,512): proj1; [512,4608): nt-load pack ---------------
__global__ __launch_bounds__(256) void kA(
    const int* __restrict__ adj, unsigned* __restrict__ mb,
    const float* __restrict__ x, const float* __restrict__ W1,
    const float* __restrict__ a1, unsigned short* __restrict__ wht1,
    float* __restrict__ ssrc1, float* __restrict__ G1g, float* __restrict__ G2g) {
  if (blockIdx.x >= 512) {
    // pack: each thread -> 16 consecutive ints via 4 nt int4 loads -> 16-bit mask
    int pb = blockIdx.x - 512;                     // 0..4095
    int t = threadIdx.x;
    const i32x4* ap = (const i32x4*)adj + ((size_t)pb * 256 + t) * 4;
    i32x4 v0 = __builtin_nontemporal_load(ap + 0);
    i32x4 v1 = __builtin_nontemporal_load(ap + 1);
    i32x4 v2 = __builtin_nontemporal_load(ap + 2);
    i32x4 v3 = __builtin_nontemporal_load(ap + 3);
    unsigned msk = 0;
    msk |= (unsigned)(v0[0] != 0) | ((unsigned)(v0[1] != 0) << 1) |
           ((unsigned)(v0[2] != 0) << 2) | ((unsigned)(v0[3] != 0) << 3);
    msk |= ((unsigned)(v1[0] != 0) << 4) | ((unsigned)(v1[1] != 0) << 5) |
           ((unsigned)(v1[2] != 0) << 6) | ((unsigned)(v1[3] != 0) << 7);
    msk |= ((unsigned)(v2[0] != 0) << 8) | ((unsigned)(v2[1] != 0) << 9) |
           ((unsigned)(v2[2] != 0) << 10) | ((unsigned)(v2[3] != 0) << 11);
    msk |= ((unsigned)(v3[0] != 0) << 12) | ((unsigned)(v3[1] != 0) << 13) |
           ((unsigned)(v3[2] != 0) << 14) | ((unsigned)(v3[3] != 0) << 15);
    unsigned other = __shfl_xor(msk, 1);
    if (!(t & 1)) mb[pb * 128 + (t >> 1)] = msk | (other << 16);
    return;
  }
  int blk = blockIdx.x;                // 0..511 proj1, 16 rows each
  int rowg = blk * 16;
  int b = rowg >> 11, rloc = rowg & (NN - 1);
  int tid = threadIdx.x, lane = tid & 63, h = tid >> 6;
  int cl = lane & 15, g = lane >> 4;

  const float* xr = x + (size_t)(rowg + cl) * 64 + 8 * g;
  bf16x8 af[2];
#pragma unroll
  for (int ks = 0; ks < 2; ++ks)
    af[ks] = cvt8(*(const f32x4*)(xr + ks * 32), *(const f32x4*)(xr + ks * 32 + 4));

  f32x4 zero = {0.f, 0.f, 0.f, 0.f};
  f32x4 acc[4] = {zero, zero, zero, zero};
#pragma unroll
  for (int ft = 0; ft < 4; ++ft) {
    const float* wr = W1 + (size_t)(h * 64 + ft * 16 + cl) * 64 + 8 * g;
#pragma unroll
    for (int ks = 0; ks < 2; ++ks) {
      bf16x8 bfr = cvt8(*(const f32x4*)(wr + ks * 32), *(const f32x4*)(wr + ks * 32 + 4));
      acc[ft] = __builtin_amdgcn_mfma_f32_16x16x32_bf16(af[ks], bfr, acc[ft], 0, 0, 0);
    }
  }
  // fragment-layout store: node J = rloc+4g+r, feat F = ft*16+cl
  unsigned short* bhb = wht1 + (size_t)(b * NH + h) * 64 * NN;
  int kb = rloc >> 5;
  int gd = ((rloc >> 3) & 2) + (g >> 1);
  int e0 = 4 * (g & 1);
  float ps[4] = {0.f, 0.f, 0.f, 0.f}, pd[4] = {0.f, 0.f, 0.f, 0.f};
#pragma unroll
  for (int ft = 0; ft < 4; ++ft) {
    float as = a1[h * 128 + ft * 16 + cl];
    float ad = a1[h * 128 + 64 + ft * 16 + cl];
    u16x4 w4;
#pragma unroll
    for (int r = 0; r < 4; ++r) {
      float v = acc[ft][r];
      w4[r] = (unsigned short)f2bf1(v);
      ps[r] += v * as; pd[r] += v * ad;
    }
    *(u16x4*)(bhb + (size_t)(kb * 4 + ft) * 512 + cl * 8 + gd * 128 + e0) = w4;
  }
#pragma unroll
  for (int r = 0; r < 4; ++r) {
    float s = ps[r], d = pd[r];
    s += __shfl_xor(s, 1); s += __shfl_xor(s, 2); s += __shfl_xor(s, 4); s += __shfl_xor(s, 8);
    d += __shfl_xor(d, 1); d += __shfl_xor(d, 2); d += __shfl_xor(d, 4); d += __shfl_xor(d, 8);
    if (cl == 0) {
      int idx = (b * NH + h) * NN + rloc + 4 * g + r;
      ssrc1[idx] = s;
      G1g[idx] = __expf(d);
      G2g[idx] = __expf(0.2f * d);
    }
  }
}

// ---------- k2: layer-1 attention. bid=[tile(5)][bh(4)] -> XCD pinned per (b,h)
// block = 64 rows, 8 waves = 4 row-tiles x 2 j-halves; 32-iter loop + prefetch
__global__ __launch_bounds__(512) void k2_attn1(
    const unsigned short* __restrict__ wht1, const float* __restrict__ ssrc1,
    const float* __restrict__ G1g, const float* __restrict__ G2g,
    const unsigned* __restrict__ mb, float* __restrict__ hout) {
  // phase 1: sdm[64][65] 16640 B | sG1 8 KB | sG2 8 KB = 33024 B
  // phase 2 (overlay): cmb[4][16][68] 17408 B + sden[4][16] 256 B
  __shared__ __align__(16) char smem[33280];
  __shared__ float swmax[8];
  unsigned (*sdm)[65] = (unsigned(*)[65])smem;
  float* sG1 = (float*)(smem + 16640);
  float* sG2 = (float*)(smem + 16640 + 8192);
  float (*cmb)[16][68] = (float(*)[16][68])smem;
  float (*sden)[16] = (float(*)[16])(smem + 17408);

  int bid = blockIdx.x;                // 512 = [tile(5 bits hi)][bh(4 bits lo)]
  int bh = bid & 15, tile = bid >> 4;  // bid%8 = bh%8 -> same XCD per (b,h)
  int b = bh >> 2, h = bh & 3;
  int rowblk = tile << 6;
  int t = threadIdx.x, lane = t & 63, w = t >> 6;
  int wloc = w & 3, jh = w >> 2;
  int cl = lane & 15, g = lane >> 4, g8 = g * 8;

  { // stage 64 rows x 64 mask words (8 words per thread)
    int row = t >> 3, c = (t & 7) * 8;
    const unsigned* mrow = mb + (size_t)(b * NN + rowblk + row) * NW + c;
    uint4 v0 = *(const uint4*)(mrow);
    uint4 v1 = *(const uint4*)(mrow + 4);
    sdm[row][c + 0] = v0.x; sdm[row][c + 1] = v0.y;
    sdm[row][c + 2] = v0.z; sdm[row][c + 3] = v0.w;
    sdm[row][c + 4] = v1.x; sdm[row][c + 5] = v1.y;
    sdm[row][c + 6] = v1.z; sdm[row][c + 7] = v1.w;
  }
  { // stage G1/G2 (2048 floats each) + block-local max of G1
    const f32x4* g1p = (const f32x4*)(G1g + (size_t)(b * NH + h) * NN);
    const f32x4* g2p = (const f32x4*)(G2g + (size_t)(b * NH + h) * NN);
    f32x4 gv = g1p[t];
    ((f32x4*)sG1)[t] = gv;
    ((f32x4*)sG2)[t] = g2p[t];
    float gmx = fmaxf(fmaxf(gv[0], gv[1]), fmaxf(gv[2], gv[3]));
    gmx = fmaxf(gmx, __shfl_xor(gmx, 1));  gmx = fmaxf(gmx, __shfl_xor(gmx, 2));
    gmx = fmaxf(gmx, __shfl_xor(gmx, 4));  gmx = fmaxf(gmx, __shfl_xor(gmx, 8));
    gmx = fmaxf(gmx, __shfl_xor(gmx, 16)); gmx = fmaxf(gmx, __shfl_xor(gmx, 32));
    if (lane == 0) swmax[w] = gmx;
  }
  int rowW = rowblk + wloc * 16;
  float s = ssrc1[(size_t)(b * NH + h) * NN + rowW + cl];
  __syncthreads();
  float mxv = fmaxf(fmaxf(fmaxf(swmax[0], swmax[1]), fmaxf(swmax[2], swmax[3])),
                    fmaxf(fmaxf(swmax[4], swmax[5]), fmaxf(swmax[6], swmax[7])));
  float logMx = __logf(mxv);
  float m = lrelu(s + logMx);          // valid per-row softmax shift (upper bound)
  float F1 = __expf(s - m), F2 = __expf(0.2f * s - m);

  short onev = (cl == 0) ? (short)0x3F80 : (short)0;
  bf16x8 ones = {onev, onev, onev, onev, onev, onev, onev, onev};
  f32x4 zero = {0.f, 0.f, 0.f, 0.f};
  f32x4 acc[4] = {zero, zero, zero, zero};
  f32x4 acc1 = zero;                   // denominator via ones column
  const unsigned short* fbase = wht1 + (size_t)(b * NH + h) * 64 * NN + lane * 8;
  int rloc = wloc * 16 + cl;
  int kb0 = jh * 32;

  bf16x8 curf[4], nxtf[4];
#pragma unroll
  for (int ft = 0; ft < 4; ++ft)
    curf[ft] = *(const bf16x8*)(fbase + (size_t)(kb0 * 4 + ft) * 512);

  for (int i = 0; i < 32; ++i) {
    int kb = kb0 + i;
    if (i < 31) {                      // prefetch next iteration's fragments
#pragma unroll
      for (int ft = 0; ft < 4; ++ft)
        nxtf[ft] = *(const bf16x8*)(fbase + (size_t)((kb + 1) * 4 + ft) * 512);
    }
    unsigned by = (sdm[rloc][kb] >> g8) & 0xFFu;
    int j0 = kb * 32 + g8;
    f32x4 g1a = *(const f32x4*)(sG1 + j0);
    f32x4 g1b = *(const f32x4*)(sG1 + j0 + 4);
    f32x4 g2a = *(const f32x4*)(sG2 + j0);
    f32x4 g2b = *(const f32x4*)(sG2 + j0 + 4);
    float wv[8];
#pragma unroll
    for (int e = 0; e < 8; ++e) {
      float g1 = (e < 4) ? g1a[e] : g1b[e - 4];
      float g2 = (e < 4) ? g2a[e] : g2b[e - 4];
      float v = fmaxf(F1 * g1, F2 * g2);   // exp(lrelu(s+t)-m), branch-free
      wv[e] = ((by >> e) & 1u) ? v : 0.f;
    }
    union { unsigned u[4]; bf16x8 v; } pa;
    pa.u[0] = pk2(wv[0], wv[1]); pa.u[1] = pk2(wv[2], wv[3]);
    pa.u[2] = pk2(wv[4], wv[5]); pa.u[3] = pk2(wv[6], wv[7]);
#pragma unroll
    for (int ft = 0; ft < 4; ++ft)
      acc[ft] = __builtin_amdgcn_mfma_f32_16x16x32_bf16(pa.v, curf[ft], acc[ft], 0, 0, 0);
    acc1 = __builtin_amdgcn_mfma_f32_16x16x32_bf16(pa.v, ones, acc1, 0, 0, 0);
#pragma unroll
    for (int ft = 0; ft < 4; ++ft) curf[ft] = nxtf[ft];
  }
  __syncthreads();                     // all LDS reads done; overlay safe
  if (jh == 1) {
#pragma unroll
    for (int ft = 0; ft < 4; ++ft)
#pragma unroll
      for (int r = 0; r < 4; ++r)
        cmb[wloc][4 * g + r][ft * 16 + cl] = acc[ft][r];
    if (cl == 0) {
#pragma unroll
      for (int r = 0; r < 4; ++r) sden[wloc][4 * g + r] = acc1[r];
    }
  }
  __syncthreads();
  if (jh == 0) {
#pragma unroll
    for (int r = 0; r < 4; ++r) {
      int rowm = 4 * g + r;
      float dself = __shfl(acc1[r], lane & 48);   // denom col 0 lives at cl==0
      float inv = 1.f / (dself + sden[wloc][rowm]);
      float* dst = hout + (size_t)(b * NN + rowW + rowm) * 256 + h * 64;
#pragma unroll
      for (int ft = 0; ft < 4; ++ft) {
        float v = (acc[ft][r] + cmb[wloc][rowm][ft * 16 + cl]) * inv;
        v = v > 0.f ? v : (__expf(v) - 1.f);      // ELU
        dst[ft * 16 + cl] = v;
      }
    }
  }
}

// ---------- k3: Wh2 = h @ W2^T via MFMA split-K; frag-layout store + scores ----
__global__ __launch_bounds__(256) void k3_proj2(
    const float* __restrict__ hin, const float* __restrict__ W2,
    const float* __restrict__ a2, unsigned short* __restrict__ wh2t,
    float* __restrict__ ssrc2, float* __restrict__ G1o, float* __restrict__ G2o) {
  __shared__ float cmb[4][16][33];
  int blk = blockIdx.x;                 // 512: 16 rows each
  int b = blk >> 7, rowbase = (blk & 127) << 4;
  int t = threadIdx.x, lane = t & 63, w = t >> 6;
  int cl = lane & 15, g = lane >> 4;
  int k0 = w * 64;                      // K split across 4 waves

  const float* hr = hin + (size_t)(b * NN + rowbase + cl) * 256 + k0 + 8 * g;
  bf16x8 af[2];
#pragma unroll
  for (int ks = 0; ks < 2; ++ks)
    af[ks] = cvt8(*(const f32x4*)(hr + ks * 32), *(const f32x4*)(hr + ks * 32 + 4));

  f32x4 zero = {0.f, 0.f, 0.f, 0.f};
  f32x4 acc[2] = {zero, zero};
#pragma unroll
  for (int ft = 0; ft < 2; ++ft) {
    const float* wr = W2 + (size_t)(ft * 16 + cl) * 256 + k0 + 8 * g;
#pragma unroll
    for (int ks = 0; ks < 2; ++ks) {
      bf16x8 bfr = cvt8(*(const f32x4*)(wr + ks * 32), *(const f32x4*)(wr + ks * 32 + 4));
      acc[ft] = __builtin_amdgcn_mfma_f32_16x16x32_bf16(af[ks], bfr, acc[ft], 0, 0, 0);
    }
  }
#pragma unroll
  for (int ft = 0; ft < 2; ++ft)
#pragma unroll
    for (int r = 0; r < 4; ++r)
      cmb[w][4 * g + r][ft * 16 + cl] = acc[ft][r];
  __syncthreads();

  int row = t >> 4, c0 = t & 15;
  float v0 = cmb[0][row][c0] + cmb[1][row][c0] + cmb[2][row][c0] + cmb[3][row][c0];
  float v1 = cmb[0][row][c0 + 16] + cmb[1][row][c0 + 16] + cmb[2][row][c0 + 16] + cmb[3][row][c0 + 16];
  float ps = v0 * a2[c0] + v1 * a2[c0 + 16];
  float pd = v0 * a2[32 + c0] + v1 * a2[32 + c0 + 16];
  ps += __shfl_xor(ps, 1); ps += __shfl_xor(ps, 2); ps += __shfl_xor(ps, 4); ps += __shfl_xor(ps, 8);
  pd += __shfl_xor(pd, 1); pd += __shfl_xor(pd, 2); pd += __shfl_xor(pd, 4); pd += __shfl_xor(pd, 8);
  if (c0 == 0) {
    int idx = b * NN + rowbase + row;
    ssrc2[idx] = ps;
    G1o[idx] = __expf(pd);
    G2o[idx] = __expf(0.2f * pd);
  }
  cmb[0][row][c0] = v0;
  cmb[0][row][c0 + 16] = v1;
  __syncthreads();
  // fragment-layout bf16 store: feat = col, nodes J = rowbase + 2*rg + {0,1}
  int col = t >> 3, rg = t & 7;
  unsigned pk = pk2(cmb[0][2 * rg][col], cmb[0][2 * rg + 1][col]);
  int kb2 = rowbase >> 5;
  int gd = ((rowbase >> 3) & 2) + (rg >> 2);
  size_t off = (size_t)(kb2 * 2 + (col >> 4)) * 512 + (col & 15) * 8 + gd * 128 + 2 * (rg & 3);
  *(unsigned*)(wh2t + (size_t)b * 32 * NN + off) = pk;
}

// ---------- k4: layer-2 attention. block = 16 rows; 8 waves = 8 j-chunks -------
__global__ __launch_bounds__(512) void k4_attn2(
    const unsigned short* __restrict__ wh2t, const float* __restrict__ ssrc2,
    const float* __restrict__ G1o, const float* __restrict__ G2o,
    const unsigned* __restrict__ mb, float* __restrict__ outp) {
  __shared__ unsigned sdm[16][65];                 // 4.2 KB
  __shared__ __align__(16) float sG1[NN], sG2[NN]; // 16 KB
  __shared__ float pacc[16 * 33];                  // 2.1 KB
  __shared__ float pden[16];
  __shared__ float swmax[8];
  int blk = blockIdx.x;                // 512: 16 rows each
  int b = blk >> 7, rowbase = (blk & 127) << 4;
  int t = threadIdx.x, lane = t & 63, w = t >> 6;
  int cl = lane & 15, g = lane >> 4, g8 = g * 8;
  { // stage 16 rows x 64 words (2 per thread)
    int row = t >> 5, c = (t & 31) * 2;
    uint2 v = *(const uint2*)(mb + (size_t)(b * NN + rowbase + row) * NW + c);
    sdm[row][c + 0] = v.x; sdm[row][c + 1] = v.y;
  }
  { // stage G + block-local max of G1
    const f32x4* g1p = (const f32x4*)(G1o + (size_t)b * NN);
    const f32x4* g2p = (const f32x4*)(G2o + (size_t)b * NN);
    f32x4 gv = g1p[t];
    ((f32x4*)sG1)[t] = gv;
    ((f32x4*)sG2)[t] = g2p[t];
    float gmx = fmaxf(fmaxf(gv[0], gv[1]), fmaxf(gv[2], gv[3]));
    gmx = fmaxf(gmx, __shfl_xor(gmx, 1));  gmx = fmaxf(gmx, __shfl_xor(gmx, 2));
    gmx = fmaxf(gmx, __shfl_xor(gmx, 4));  gmx = fmaxf(gmx, __shfl_xor(gmx, 8));
    gmx = fmaxf(gmx, __shfl_xor(gmx, 16)); gmx = fmaxf(gmx, __shfl_xor(gmx, 32));
    if (lane == 0) swmax[w] = gmx;
  }
  for (int i = t; i < 16 * 33; i += 512) pacc[i] = 0.f;
  if (t < 16) pden[t] = 0.f;
  float s = ssrc2[b * NN + rowbase + cl];
  __syncthreads();
  float mxv = fmaxf(fmaxf(fmaxf(swmax[0], swmax[1]), fmaxf(swmax[2], swmax[3])),
                    fmaxf(fmaxf(swmax[4], swmax[5]), fmaxf(swmax[6], swmax[7])));
  float logMx = __logf(mxv);
  float m = lrelu(s + logMx);
  float F1 = __expf(s - m), F2 = __expf(0.2f * s - m);

  short onev = (cl == 0) ? (short)0x3F80 : (short)0;
  bf16x8 ones = {onev, onev, onev, onev, onev, onev, onev, onev};
  f32x4 zero = {0.f, 0.f, 0.f, 0.f};
  f32x4 acc[2] = {zero, zero};
  f32x4 acc1 = zero;
  const unsigned short* fbase = wh2t + (size_t)b * 32 * NN + lane * 8;
  int kb0 = w * 8;

  bf16x8 curf[2], nxtf[2];
#pragma unroll
  for (int ft = 0; ft < 2; ++ft)
    curf[ft] = *(const bf16x8*)(fbase + (size_t)(kb0 * 2 + ft) * 512);

  for (int i = 0; i < 8; ++i) {
    int kb = kb0 + i;
    if (i < 7) {
#pragma unroll
      for (int ft = 0; ft < 2; ++ft)
        nxtf[ft] = *(const bf16x8*)(fbase + (size_t)((kb + 1) * 2 + ft) * 512);
    }
    unsigned by = (sdm[cl][kb] >> g8) & 0xFFu;
    int j0 = kb * 32 + g8;
    f32x4 g1a = *(const f32x4*)(sG1 + j0);
    f32x4 g1b = *(const f32x4*)(sG1 + j0 + 4);
    f32x4 g2a = *(const f32x4*)(sG2 + j0);
    f32x4 g2b = *(const f32x4*)(sG2 + j0 + 4);
    float wv[8];
#pragma unroll
    for (int e = 0; e < 8; ++e) {
      float g1 = (e < 4) ? g1a[e] : g1b[e - 4];
      float g2 = (e < 4) ? g2a[e] : g2b[e - 4];
      float v = fmaxf(F1 * g1, F2 * g2);
      wv[e] = ((by >> e) & 1u) ? v : 0.f;
    }
    union { unsigned u[4]; bf16x8 v; } pa;
    pa.u[0] = pk2(wv[0], wv[1]); pa.u[1] = pk2(wv[2], wv[3]);
    pa.u[2] = pk2(wv[4], wv[5]); pa.u[3] = pk2(wv[6], wv[7]);
#pragma unroll
    for (int ft = 0; ft < 2; ++ft)
      acc[ft] = __builtin_amdgcn_mfma_f32_16x16x32_bf16(pa.v, curf[ft], acc[ft], 0, 0, 0);
    acc1 = __builtin_amdgcn_mfma_f32_16x16x32_bf16(pa.v, ones, acc1, 0, 0, 0);
#pragma unroll
    for (int ft = 0; ft < 2; ++ft) curf[ft] = nxtf[ft];
  }
#pragma unroll
  for (int ft = 0; ft < 2; ++ft)
#pragma unroll
    for (int r = 0; r < 4; ++r)
      atomicAdd(&pacc[(4 * g + r) * 33 + ft * 16 + cl], acc[ft][r]);
  if (cl == 0) {
#pragma unroll
    for (int r = 0; r < 4; ++r) atomicAdd(&pden[4 * g + r], acc1[r]);
  }
  __syncthreads();
  { // epilogue: 512 threads x 1 value
    int row = t >> 5, f = t & 31;
    outp[(size_t)(b * NN + rowbase + row) * 32 + f] = pacc[row * 33 + f] / pden[row];
  }
}

extern "C" void kernel_launch(void* const* d_in, const int* in_sizes, int n_in,
                              void* d_out, int out_size, void* d_ws, size_t ws_size,
                              hipStream_t stream) {
  (void)in_sizes; (void)n_in; (void)out_size; (void)ws_size;
  const float* x   = (const float*)d_in[0];
  const int*   adj = (const int*)d_in[1];
  const float* W1  = (const float*)d_in[2];
  const float* a1  = (const float*)d_in[3];
  const float* W2  = (const float*)d_in[4];
  const float* a2  = (const float*)d_in[5];
  float* outp = (float*)d_out;
  char* ws = (char*)d_ws;

  unsigned*       mbits = (unsigned*)(ws);                                   // 2 MB
  unsigned short* wht1  = (unsigned short*)(ws + (size_t)(2u << 20));        // 4 MB
  float*          ssrc1 = (float*)(ws + (size_t)(6u << 20));                 // 128 KB
  float*          G1g   = (float*)(ws + (size_t)(6u << 20) + (128u << 10));  // 128 KB
  float*          G2g   = (float*)(ws + (size_t)(6u << 20) + (256u << 10));  // 128 KB
  float*          hbuf  = (float*)(ws + (size_t)(6u << 20) + (512u << 10));  // 8 MB
  unsigned short* wh2t  = (unsigned short*)(ws + (size_t)(14u << 20) + (512u << 10)); // 512 KB
  float*          ssrc2 = (float*)(ws + (size_t)(15u << 20));                // 32 KB
  float*          G1o   = (float*)(ws + (size_t)(15u << 20) + (32u << 10));  // 32 KB
  float*          G2o   = (float*)(ws + (size_t)(15u << 20) + (64u << 10));  // 32 KB

  kA      <<<4608, 256, 0, stream>>>(adj, mbits, x, W1, a1, wht1, ssrc1, G1g, G2g);
  k2_attn1<<<512,  512, 0, stream>>>(wht1, ssrc1, G1g, G2g, mbits, hbuf);
  k3_proj2<<<512,  256, 0, stream>>>(hbuf, W2, a2, wh2t, ssrc2, G1o, G2o);
  k4_attn2<<<512,  512, 0, stream>>>(wh2t, ssrc2, G1o, G2o, mbits, outp);
}

// Round 8
// 165.854 us; speedup vs baseline: 1.1999x; 1.0147x over previous
//
#include <hip/hip_runtime.h>
#include <hip/hip_bf16.h>
#include <cstdint>

#define NN 2048
#define NH 4
#define NW 64   // mask words per row

typedef __attribute__((ext_vector_type(8))) short bf16x8;
typedef __attribute__((ext_vector_type(4))) float f32x4;
typedef __attribute__((ext_vector_type(4))) int i32x4;
typedef __attribute__((ext_vector_type(4))) unsigned short u16x4;

__device__ __forceinline__ float lrelu(float s) { return s > 0.f ? s : 0.2f * s; }

__device__ __forceinline__ unsigned pk2(float lo, float hi) {
  __hip_bfloat162 h2 = __float22bfloat162_rn(make_float2(lo, hi));
  union { __hip_bfloat162 h; unsigned u; } c; c.h = h2; return c.u;
}
__device__ __forceinline__ unsigned short f2bf1(float f) {
  __hip_bfloat16 h = __float2bfloat16(f);
  union { __hip_bfloat16 h; unsigned short u; } c; c.h = h; return c.u;
}
__device__ __forceinline__ bf16x8 cvt8(f32x4 v0, f32x4 v1) {
  union { unsigned u[4]; bf16x8 v; } r;
  r.u[0] = pk2(v0[0], v0[1]); r.u[1] = pk2(v0[2], v0[3]);
  r.u[2] = pk2(v1[0], v1[1]); r.u[3] = pk2(v1[2], v1[3]);
  return r.v;
}

// Fragment layout for Wh^T (per (b,h) slab of F feats x 2048 nodes):
// short index = (kb*FT + ft)*512 + (feat&15)*8 + gd*128 + e  with node = kb*32+8*gd+e
// -> k-attn lane `lane` loads 16B at frag_base + (kb*FT+ft)*512 + lane*8
//    holding feat = ft*16 + (lane&15), nodes = kb*32 + (lane>>4)*8 .. +7 (B-frag order)

// ---------- kA: blocks [0,512): proj1; [512,2560): pack (32 ints -> 1 word/thr)
__global__ __launch_bounds__(256) void kA(
    const int* __restrict__ adj, unsigned* __restrict__ mb,
    const float* __restrict__ x, const float* __restrict__ W1,
    const float* __restrict__ a1, unsigned short* __restrict__ wht1,
    float* __restrict__ ssrc1, float* __restrict__ G1g, float* __restrict__ G2g) {
  if (blockIdx.x >= 512) {
    // pack: each thread owns one 32-bit mask word = 32 consecutive adj ints,
    // 8 outstanding nt int4 loads, no cross-lane ops, coalesced 4B/lane store.
    size_t gid = (size_t)(blockIdx.x - 512) * 256 + threadIdx.x;  // word index
    const i32x4* ap = (const i32x4*)adj + gid * 8;
    i32x4 v0 = __builtin_nontemporal_load(ap + 0);
    i32x4 v1 = __builtin_nontemporal_load(ap + 1);
    i32x4 v2 = __builtin_nontemporal_load(ap + 2);
    i32x4 v3 = __builtin_nontemporal_load(ap + 3);
    i32x4 v4 = __builtin_nontemporal_load(ap + 4);
    i32x4 v5 = __builtin_nontemporal_load(ap + 5);
    i32x4 v6 = __builtin_nontemporal_load(ap + 6);
    i32x4 v7 = __builtin_nontemporal_load(ap + 7);
    unsigned word = 0;
#pragma unroll
    for (int j = 0; j < 4; ++j) {
      word |= ((unsigned)(v0[j] != 0)) << (0 + j);
      word |= ((unsigned)(v1[j] != 0)) << (4 + j);
      word |= ((unsigned)(v2[j] != 0)) << (8 + j);
      word |= ((unsigned)(v3[j] != 0)) << (12 + j);
      word |= ((unsigned)(v4[j] != 0)) << (16 + j);
      word |= ((unsigned)(v5[j] != 0)) << (20 + j);
      word |= ((unsigned)(v6[j] != 0)) << (24 + j);
      word |= ((unsigned)(v7[j] != 0)) << (28 + j);
    }
    mb[gid] = word;
    return;
  }
  int blk = blockIdx.x;                // 0..511 proj1, 16 rows each
  int rowg = blk * 16;
  int b = rowg >> 11, rloc = rowg & (NN - 1);
  int tid = threadIdx.x, lane = tid & 63, h = tid >> 6;
  int cl = lane & 15, g = lane >> 4;

  const float* xr = x + (size_t)(rowg + cl) * 64 + 8 * g;
  bf16x8 af[2];
#pragma unroll
  for (int ks = 0; ks < 2; ++ks)
    af[ks] = cvt8(*(const f32x4*)(xr + ks * 32), *(const f32x4*)(xr + ks * 32 + 4));

  f32x4 zero = {0.f, 0.f, 0.f, 0.f};
  f32x4 acc[4] = {zero, zero, zero, zero};
#pragma unroll
  for (int ft = 0; ft < 4; ++ft) {
    const float* wr = W1 + (size_t)(h * 64 + ft * 16 + cl) * 64 + 8 * g;
#pragma unroll
    for (int ks = 0; ks < 2; ++ks) {
      bf16x8 bfr = cvt8(*(const f32x4*)(wr + ks * 32), *(const f32x4*)(wr + ks * 32 + 4));
      acc[ft] = __builtin_amdgcn_mfma_f32_16x16x32_bf16(af[ks], bfr, acc[ft], 0, 0, 0);
    }
  }
  // fragment-layout store: node J = rloc+4g+r, feat F = ft*16+cl
  unsigned short* bhb = wht1 + (size_t)(b * NH + h) * 64 * NN;
  int kb = rloc >> 5;
  int gd = ((rloc >> 3) & 2) + (g >> 1);
  int e0 = 4 * (g & 1);
  float ps[4] = {0.f, 0.f, 0.f, 0.f}, pd[4] = {0.f, 0.f, 0.f, 0.f};
#pragma unroll
  for (int ft = 0; ft < 4; ++ft) {
    float as = a1[h * 128 + ft * 16 + cl];
    float ad = a1[h * 128 + 64 + ft * 16 + cl];
    u16x4 w4;
#pragma unroll
    for (int r = 0; r < 4; ++r) {
      float v = acc[ft][r];
      w4[r] = f2bf1(v);
      ps[r] += v * as; pd[r] += v * ad;
    }
    *(u16x4*)(bhb + (size_t)(kb * 4 + ft) * 512 + cl * 8 + gd * 128 + e0) = w4;
  }
#pragma unroll
  for (int r = 0; r < 4; ++r) {
    float s = ps[r], d = pd[r];
    s += __shfl_xor(s, 1); s += __shfl_xor(s, 2); s += __shfl_xor(s, 4); s += __shfl_xor(s, 8);
    d += __shfl_xor(d, 1); d += __shfl_xor(d, 2); d += __shfl_xor(d, 4); d += __shfl_xor(d, 8);
    if (cl == 0) {
      int idx = (b * NH + h) * NN + rloc + 4 * g + r;
      ssrc1[idx] = s;
      G1g[idx] = __expf(d);
      G2g[idx] = __expf(0.2f * d);
    }
  }
}

// ---------- k2: layer-1 attention. bid=[tile(5)][bh(4)] -> XCD pinned per (b,h)
// block = 64 rows, 8 waves = 4 row-tiles x 2 j-halves; 32-iter loop + prefetch
__global__ __launch_bounds__(512) void k2_attn1(
    const unsigned short* __restrict__ wht1, const float* __restrict__ ssrc1,
    const float* __restrict__ G1g, const float* __restrict__ G2g,
    const unsigned* __restrict__ mb, unsigned short* __restrict__ hout) {
  // phase 1: sdm[64][65] 16640 B | sG1 8 KB | sG2 8 KB = 33024 B
  // phase 2 (overlay): cmb[4][16][68] 17408 B + sden[4][16] 256 B
  __shared__ __align__(16) char smem[33280];
  __shared__ float swmax[8];
  unsigned (*sdm)[65] = (unsigned(*)[65])smem;
  float* sG1 = (float*)(smem + 16640);
  float* sG2 = (float*)(smem + 16640 + 8192);
  float (*cmb)[16][68] = (float(*)[16][68])smem;
  float (*sden)[16] = (float(*)[16])(smem + 17408);

  int bid = blockIdx.x;                // 512 = [tile(5 bits hi)][bh(4 bits lo)]
  int bh = bid & 15, tile = bid >> 4;  // bid%8 = bh%8 -> same XCD per (b,h)
  int b = bh >> 2, h = bh & 3;
  int rowblk = tile << 6;
  int t = threadIdx.x, lane = t & 63, w = t >> 6;
  int wloc = w & 3, jh = w >> 2;
  int cl = lane & 15, g = lane >> 4, g8 = g * 8;

  { // stage 64 rows x 64 mask words (8 words per thread)
    int row = t >> 3, c = (t & 7) * 8;
    const unsigned* mrow = mb + (size_t)(b * NN + rowblk + row) * NW + c;
    uint4 v0 = *(const uint4*)(mrow);
    uint4 v1 = *(const uint4*)(mrow + 4);
    sdm[row][c + 0] = v0.x; sdm[row][c + 1] = v0.y;
    sdm[row][c + 2] = v0.z; sdm[row][c + 3] = v0.w;
    sdm[row][c + 4] = v1.x; sdm[row][c + 5] = v1.y;
    sdm[row][c + 6] = v1.z; sdm[row][c + 7] = v1.w;
  }
  { // stage G1/G2 (2048 floats each) + block-local max of G1
    const f32x4* g1p = (const f32x4*)(G1g + (size_t)(b * NH + h) * NN);
    const f32x4* g2p = (const f32x4*)(G2g + (size_t)(b * NH + h) * NN);
    f32x4 gv = g1p[t];
    ((f32x4*)sG1)[t] = gv;
    ((f32x4*)sG2)[t] = g2p[t];
    float gmx = fmaxf(fmaxf(gv[0], gv[1]), fmaxf(gv[2], gv[3]));
    gmx = fmaxf(gmx, __shfl_xor(gmx, 1));  gmx = fmaxf(gmx, __shfl_xor(gmx, 2));
    gmx = fmaxf(gmx, __shfl_xor(gmx, 4));  gmx = fmaxf(gmx, __shfl_xor(gmx, 8));
    gmx = fmaxf(gmx, __shfl_xor(gmx, 16)); gmx = fmaxf(gmx, __shfl_xor(gmx, 32));
    if (lane == 0) swmax[w] = gmx;
  }
  int rowW = rowblk + wloc * 16;
  float s = ssrc1[(size_t)(b * NH + h) * NN + rowW + cl];
  __syncthreads();
  float mxv = fmaxf(fmaxf(fmaxf(swmax[0], swmax[1]), fmaxf(swmax[2], swmax[3])),
                    fmaxf(fmaxf(swmax[4], swmax[5]), fmaxf(swmax[6], swmax[7])));
  float logMx = __logf(mxv);
  float m = lrelu(s + logMx);          // valid per-row softmax shift (upper bound)
  float F1 = __expf(s - m), F2 = __expf(0.2f * s - m);

  short onev = (cl == 0) ? (short)0x3F80 : (short)0;
  bf16x8 ones = {onev, onev, onev, onev, onev, onev, onev, onev};
  f32x4 zero = {0.f, 0.f, 0.f, 0.f};
  f32x4 acc[4] = {zero, zero, zero, zero};
  f32x4 acc1 = zero;                   // denominator via ones column
  const unsigned short* fbase = wht1 + (size_t)(b * NH + h) * 64 * NN + lane * 8;
  int rloc = wloc * 16 + cl;
  int kb0 = jh * 32;

  bf16x8 curf[4], nxtf[4];
#pragma unroll
  for (int ft = 0; ft < 4; ++ft)
    curf[ft] = *(const bf16x8*)(fbase + (size_t)(kb0 * 4 + ft) * 512);

  for (int i = 0; i < 32; ++i) {
    int kb = kb0 + i;
    if (i < 31) {                      // prefetch next iteration's fragments
#pragma unroll
      for (int ft = 0; ft < 4; ++ft)
        nxtf[ft] = *(const bf16x8*)(fbase + (size_t)((kb + 1) * 4 + ft) * 512);
    }
    unsigned by = (sdm[rloc][kb] >> g8) & 0xFFu;
    int j0 = kb * 32 + g8;
    f32x4 g1a = *(const f32x4*)(sG1 + j0);
    f32x4 g1b = *(const f32x4*)(sG1 + j0 + 4);
    f32x4 g2a = *(const f32x4*)(sG2 + j0);
    f32x4 g2b = *(const f32x4*)(sG2 + j0 + 4);
    float wv[8];
#pragma unroll
    for (int e = 0; e < 8; ++e) {
      float g1 = (e < 4) ? g1a[e] : g1b[e - 4];
      float g2 = (e < 4) ? g2a[e] : g2b[e - 4];
      float v = fmaxf(F1 * g1, F2 * g2);   // exp(lrelu(s+t)-m), branch-free
      wv[e] = ((by >> e) & 1u) ? v : 0.f;
    }
    union { unsigned u[4]; bf16x8 v; } pa;
    pa.u[0] = pk2(wv[0], wv[1]); pa.u[1] = pk2(wv[2], wv[3]);
    pa.u[2] = pk2(wv[4], wv[5]); pa.u[3] = pk2(wv[6], wv[7]);
#pragma unroll
    for (int ft = 0; ft < 4; ++ft)
      acc[ft] = __builtin_amdgcn_mfma_f32_16x16x32_bf16(pa.v, curf[ft], acc[ft], 0, 0, 0);
    acc1 = __builtin_amdgcn_mfma_f32_16x16x32_bf16(pa.v, ones, acc1, 0, 0, 0);
#pragma unroll
    for (int ft = 0; ft < 4; ++ft) curf[ft] = nxtf[ft];
  }
  __syncthreads();                     // all LDS reads done; overlay safe
  if (jh == 1) {
#pragma unroll
    for (int ft = 0; ft < 4; ++ft)
#pragma unroll
      for (int r = 0; r < 4; ++r)
        cmb[wloc][4 * g + r][ft * 16 + cl] = acc[ft][r];
    if (cl == 0) {
#pragma unroll
      for (int r = 0; r < 4; ++r) sden[wloc][4 * g + r] = acc1[r];
    }
  }
  __syncthreads();
  if (jh == 0) {
#pragma unroll
    for (int r = 0; r < 4; ++r) {
      int rowm = 4 * g + r;
      float dself = __shfl(acc1[r], lane & 48);   // denom col 0 lives at cl==0
      float inv = 1.f / (dself + sden[wloc][rowm]);
      unsigned short* dst = hout + (size_t)(b * NN + rowW + rowm) * 256 + h * 64;
#pragma unroll
      for (int ft = 0; ft < 4; ++ft) {
        float v = (acc[ft][r] + cmb[wloc][rowm][ft * 16 + cl]) * inv;
        v = v > 0.f ? v : (__expf(v) - 1.f);      // ELU
        dst[ft * 16 + cl] = f2bf1(v);             // bf16 (k3 rounds here anyway)
      }
    }
  }
}

// ---------- k3: Wh2 = h @ W2^T via MFMA split-K; frag-layout store + scores ----
__global__ __launch_bounds__(256) void k3_proj2(
    const unsigned short* __restrict__ hin, const float* __restrict__ W2,
    const float* __restrict__ a2, unsigned short* __restrict__ wh2t,
    float* __restrict__ ssrc2, float* __restrict__ G1o, float* __restrict__ G2o) {
  __shared__ float cmb[4][16][33];
  int blk = blockIdx.x;                 // 512: 16 rows each
  int b = blk >> 7, rowbase = (blk & 127) << 4;
  int t = threadIdx.x, lane = t & 63, w = t >> 6;
  int cl = lane & 15, g = lane >> 4;
  int k0 = w * 64;                      // K split across 4 waves

  const unsigned short* hr = hin + (size_t)(b * NN + rowbase + cl) * 256 + k0 + 8 * g;
  bf16x8 af[2];
#pragma unroll
  for (int ks = 0; ks < 2; ++ks)
    af[ks] = *(const bf16x8*)(hr + ks * 32);       // bf16 direct A-fragment

  f32x4 zero = {0.f, 0.f, 0.f, 0.f};
  f32x4 acc[2] = {zero, zero};
#pragma unroll
  for (int ft = 0; ft < 2; ++ft) {
    const float* wr = W2 + (size_t)(ft * 16 + cl) * 256 + k0 + 8 * g;
#pragma unroll
    for (int ks = 0; ks < 2; ++ks) {
      bf16x8 bfr = cvt8(*(const f32x4*)(wr + ks * 32), *(const f32x4*)(wr + ks * 32 + 4));
      acc[ft] = __builtin_amdgcn_mfma_f32_16x16x32_bf16(af[ks], bfr, acc[ft], 0, 0, 0);
    }
  }
#pragma unroll
  for (int ft = 0; ft < 2; ++ft)
#pragma unroll
    for (int r = 0; r < 4; ++r)
      cmb[w][4 * g + r][ft * 16 + cl] = acc[ft][r];
  __syncthreads();

  int row = t >> 4, c0 = t & 15;
  float v0 = cmb[0][row][c0] + cmb[1][row][c0] + cmb[2][row][c0] + cmb[3][row][c0];
  float v1 = cmb[0][row][c0 + 16] + cmb[1][row][c0 + 16] + cmb[2][row][c0 + 16] + cmb[3][row][c0 + 16];
  float ps = v0 * a2[c0] + v1 * a2[c0 + 16];
  float pd = v0 * a2[32 + c0] + v1 * a2[32 + c0 + 16];
  ps += __shfl_xor(ps, 1); ps += __shfl_xor(ps, 2); ps += __shfl_xor(ps, 4); ps += __shfl_xor(ps, 8);
  pd += __shfl_xor(pd, 1); pd += __shfl_xor(pd, 2); pd += __shfl_xor(pd, 4); pd += __shfl_xor(pd, 8);
  if (c0 == 0) {
    int idx = b * NN + rowbase + row;
    ssrc2[idx] = ps;
    G1o[idx] = __expf(pd);
    G2o[idx] = __expf(0.2f * pd);
  }
  cmb[0][row][c0] = v0;
  cmb[0][row][c0 + 16] = v1;
  __syncthreads();
  // fragment-layout bf16 store: feat = col, nodes J = rowbase + 2*rg + {0,1}
  int col = t >> 3, rg = t & 7;
  unsigned pk = pk2(cmb[0][2 * rg][col], cmb[0][2 * rg + 1][col]);
  int kb2 = rowbase >> 5;
  int gd = ((rowbase >> 3) & 2) + (rg >> 2);
  size_t off = (size_t)(kb2 * 2 + (col >> 4)) * 512 + (col & 15) * 8 + gd * 128 + 2 * (rg & 3);
  *(unsigned*)(wh2t + (size_t)b * 32 * NN + off) = pk;
}

// ---------- k4: layer-2 attention. block = 32 rows; 8 waves = 2 rowtiles x 4 jq
__global__ __launch_bounds__(512) void k4_attn2(
    const unsigned short* __restrict__ wh2t, const float* __restrict__ ssrc2,
    const float* __restrict__ G1o, const float* __restrict__ G2o,
    const unsigned* __restrict__ mb, float* __restrict__ outp) {
  // phase 1: sdm[32][65] 8320 B | sG1 8 KB | sG2 8 KB = 24704 B
  // phase 2 (overlay): cmb[3][2][16][36] 13824 B + sden[3][2][16] 384 B
  __shared__ __align__(16) char smem[24704];
  __shared__ float swmax[8];
  unsigned (*sdm)[65] = (unsigned(*)[65])smem;
  float* sG1 = (float*)(smem + 8320);
  float* sG2 = (float*)(smem + 8320 + 8192);
  float (*cmb)[2][16][36] = (float(*)[2][16][36])smem;
  float (*sden)[2][16] = (float(*)[2][16])(smem + 13824);

  int bid = blockIdx.x;                // 256 = [tile(6 hi)][b(2 lo)]
  int b = bid & 3, tile = bid >> 2;
  int rowblk = tile << 5;
  int t = threadIdx.x, lane = t & 63, w = t >> 6;
  int wloc = w & 1, jh = w >> 1;       // rowtile, j-quarter
  int cl = lane & 15, g = lane >> 4, g8 = g * 8;

  { // stage 32 rows x 64 mask words (4 per thread)
    int row = t >> 4, c = (t & 15) * 4;
    uint4 v = *(const uint4*)(mb + (size_t)(b * NN + rowblk + row) * NW + c);
    sdm[row][c + 0] = v.x; sdm[row][c + 1] = v.y;
    sdm[row][c + 2] = v.z; sdm[row][c + 3] = v.w;
  }
  { // stage G + block-local max of G1
    f32x4 gv = ((const f32x4*)(G1o + (size_t)b * NN))[t];
    ((f32x4*)sG1)[t] = gv;
    ((f32x4*)sG2)[t] = ((const f32x4*)(G2o + (size_t)b * NN))[t];
    float gmx = fmaxf(fmaxf(gv[0], gv[1]), fmaxf(gv[2], gv[3]));
    gmx = fmaxf(gmx, __shfl_xor(gmx, 1));  gmx = fmaxf(gmx, __shfl_xor(gmx, 2));
    gmx = fmaxf(gmx, __shfl_xor(gmx, 4));  gmx = fmaxf(gmx, __shfl_xor(gmx, 8));
    gmx = fmaxf(gmx, __shfl_xor(gmx, 16)); gmx = fmaxf(gmx, __shfl_xor(gmx, 32));
    if (lane == 0) swmax[w] = gmx;
  }
  int rowW = rowblk + wloc * 16;
  float s = ssrc2[b * NN + rowW + cl];
  __syncthreads();
  float mxv = fmaxf(fmaxf(fmaxf(swmax[0], swmax[1]), fmaxf(swmax[2], swmax[3])),
                    fmaxf(fmaxf(swmax[4], swmax[5]), fmaxf(swmax[6], swmax[7])));
  float logMx = __logf(mxv);
  float m = lrelu(s + logMx);
  float F1 = __expf(s - m), F2 = __expf(0.2f * s - m);

  short onev = (cl == 0) ? (short)0x3F80 : (short)0;
  bf16x8 ones = {onev, onev, onev, onev, onev, onev, onev, onev};
  f32x4 zero = {0.f, 0.f, 0.f, 0.f};
  f32x4 acc[2] = {zero, zero};
  f32x4 acc1 = zero;
  const unsigned short* fbase = wh2t + (size_t)b * 32 * NN + lane * 8;
  int rloc = wloc * 16 + cl;
  int kb0 = jh * 16;

  bf16x8 curf[2], nxtf[2];
#pragma unroll
  for (int ft = 0; ft < 2; ++ft)
    curf[ft] = *(const bf16x8*)(fbase + (size_t)(kb0 * 2 + ft) * 512);

  for (int i = 0; i < 16; ++i) {
    int kb = kb0 + i;
    if (i < 15) {
#pragma unroll
      for (int ft = 0; ft < 2; ++ft)
        nxtf[ft] = *(const bf16x8*)(fbase + (size_t)((kb + 1) * 2 + ft) * 512);
    }
    unsigned by = (sdm[rloc][kb] >> g8) & 0xFFu;
    int j0 = kb * 32 + g8;
    f32x4 g1a = *(const f32x4*)(sG1 + j0);
    f32x4 g1b = *(const f32x4*)(sG1 + j0 + 4);
    f32x4 g2a = *(const f32x4*)(sG2 + j0);
    f32x4 g2b = *(const f32x4*)(sG2 + j0 + 4);
    float wv[8];
#pragma unroll
    for (int e = 0; e < 8; ++e) {
      float g1 = (e < 4) ? g1a[e] : g1b[e - 4];
      float g2 = (e < 4) ? g2a[e] : g2b[e - 4];
      float v = fmaxf(F1 * g1, F2 * g2);
      wv[e] = ((by >> e) & 1u) ? v : 0.f;
    }
    union { unsigned u[4]; bf16x8 v; } pa;
    pa.u[0] = pk2(wv[0], wv[1]); pa.u[1] = pk2(wv[2], wv[3]);
    pa.u[2] = pk2(wv[4], wv[5]); pa.u[3] = pk2(wv[6], wv[7]);
#pragma unroll
    for (int ft = 0; ft < 2; ++ft)
      acc[ft] = __builtin_amdgcn_mfma_f32_16x16x32_bf16(pa.v, curf[ft], acc[ft], 0, 0, 0);
    acc1 = __builtin_amdgcn_mfma_f32_16x16x32_bf16(pa.v, ones, acc1, 0, 0, 0);
#pragma unroll
    for (int ft = 0; ft < 2; ++ft) curf[ft] = nxtf[ft];
  }
  __syncthreads();                     // all LDS reads done; overlay safe
  if (jh > 0) {
#pragma unroll
    for (int ft = 0; ft < 2; ++ft)
#pragma unroll
      for (int r = 0; r < 4; ++r)
        cmb[jh - 1][wloc][4 * g + r][ft * 16 + cl] = acc[ft][r];
    if (cl == 0) {
#pragma unroll
      for (int r = 0; r < 4; ++r) sden[jh - 1][wloc][4 * g + r] = acc1[r];
    }
  }
  __syncthreads();
  if (jh == 0) {
#pragma unroll
    for (int r = 0; r < 4; ++r) {
      int rowm = 4 * g + r;
      float dself = __shfl(acc1[r], lane & 48);
      float den = dself + sden[0][wloc][rowm] + sden[1][wloc][rowm] + sden[2][wloc][rowm];
      float inv = 1.f / den;
      float* dst = outp + (size_t)(b * NN + rowW + rowm) * 32;
#pragma unroll
      for (int ft = 0; ft < 2; ++ft) {
        float v = acc[ft][r] + cmb[0][wloc][rowm][ft * 16 + cl] +
                  cmb[1][wloc][rowm][ft * 16 + cl] + cmb[2][wloc][rowm][ft * 16 + cl];
        dst[ft * 16 + cl] = v * inv;
      }
    }
  }
}

extern "C" void kernel_launch(void* const* d_in, const int* in_sizes, int n_in,
                              void* d_out, int out_size, void* d_ws, size_t ws_size,
                              hipStream_t stream) {
  (void)in_sizes; (void)n_in; (void)out_size; (void)ws_size;
  const float* x   = (const float*)d_in[0];
  const int*   adj = (const int*)d_in[1];
  const float* W1  = (const float*)d_in[2];
  const float* a1  = (const float*)d_in[3];
  const float* W2  = (const float*)d_in[4];
  const float* a2  = (const float*)d_in[5];
  float* outp = (float*)d_out;
  char* ws = (char*)d_ws;

  unsigned*       mbits = (unsigned*)(ws);                                   // 2 MB
  unsigned short* wht1  = (unsigned short*)(ws + (size_t)(2u << 20));        // 4 MB
  float*          ssrc1 = (float*)(ws + (size_t)(6u << 20));                 // 128 KB
  float*          G1g   = (float*)(ws + (size_t)(6u << 20) + (128u << 10));  // 128 KB
  float*          G2g   = (float*)(ws + (size_t)(6u << 20) + (256u << 10));  // 128 KB
  unsigned short* hbuf  = (unsigned short*)(ws + (size_t)(6u << 20) + (512u << 10)); // 4 MB bf16
  unsigned short* wh2t  = (unsigned short*)(ws + (size_t)(14u << 20) + (512u << 10)); // 512 KB
  float*          ssrc2 = (float*)(ws + (size_t)(15u << 20));                // 32 KB
  float*          G1o   = (float*)(ws + (size_t)(15u << 20) + (32u << 10));  // 32 KB
  float*          G2o   = (float*)(ws + (size_t)(15u << 20) + (64u << 10));  // 32 KB

  kA      <<<2560, 256, 0, stream>>>(adj, mbits, x, W1, a1, wht1, ssrc1, G1g, G2g);
  k2_attn1<<<512,  512, 0, stream>>>(wht1, ssrc1, G1g, G2g, mbits, hbuf);
  k3_proj2<<<512,  256, 0, stream>>>(hbuf, W2, a2, wh2t, ssrc2, G1o, G2o);
  k4_attn2<<<256,  512, 0, stream>>>(wh2t, ssrc2, G1o, G2o, mbits, outp);
}

// Round 9
// 164.830 us; speedup vs baseline: 1.2073x; 1.0062x over previous
//
#include <hip/hip_runtime.h>
#include <hip/hip_bf16.h>
#include <cstdint>

#define NN 2048
#define NH 4
#define NW 64   // mask words per row

typedef __attribute__((ext_vector_type(8))) short bf16x8;
typedef __attribute__((ext_vector_type(4))) float f32x4;
typedef __attribute__((ext_vector_type(4))) int i32x4;
typedef __attribute__((ext_vector_type(4))) unsigned short u16x4;

__device__ __forceinline__ float lrelu(float s) { return s > 0.f ? s : 0.2f * s; }

__device__ __forceinline__ unsigned pk2(float lo, float hi) {
  __hip_bfloat162 h2 = __float22bfloat162_rn(make_float2(lo, hi));
  union { __hip_bfloat162 h; unsigned u; } c; c.h = h2; return c.u;
}
__device__ __forceinline__ unsigned short f2bf1(float f) {
  __hip_bfloat16 h = __float2bfloat16(f);
  union { __hip_bfloat16 h; unsigned short u; } c; c.h = h; return c.u;
}
__device__ __forceinline__ bf16x8 cvt8(f32x4 v0, f32x4 v1) {
  union { unsigned u[4]; bf16x8 v; } r;
  r.u[0] = pk2(v0[0], v0[1]); r.u[1] = pk2(v0[2], v0[3]);
  r.u[2] = pk2(v1[0], v1[1]); r.u[3] = pk2(v1[2], v1[3]);
  return r.v;
}

// Fragment layout for Wh^T (per (b,h) slab of F feats x 2048 nodes):
// short index = (kb*FT + ft)*512 + (feat&15)*8 + gd*128 + e  with node = kb*32+8*gd+e
// -> k-attn lane `lane` loads 16B at frag_base + (kb*FT+ft)*512 + lane*8
//    holding feat = ft*16 + (lane&15), nodes = kb*32 + (lane>>4)*8 .. +7 (B-frag order)

// ---------- kA: blocks [0,512): proj1; [512,2560): pack (32 ints -> 1 word/thr)
__global__ __launch_bounds__(256) void kA(
    const int* __restrict__ adj, unsigned* __restrict__ mb,
    const float* __restrict__ x, const float* __restrict__ W1,
    const float* __restrict__ a1, unsigned short* __restrict__ wht1,
    float* __restrict__ ssrc1, float* __restrict__ G1g, float* __restrict__ G2g) {
  if (blockIdx.x >= 512) {
    size_t gid = (size_t)(blockIdx.x - 512) * 256 + threadIdx.x;  // word index
    const i32x4* ap = (const i32x4*)adj + gid * 8;
    i32x4 v0 = __builtin_nontemporal_load(ap + 0);
    i32x4 v1 = __builtin_nontemporal_load(ap + 1);
    i32x4 v2 = __builtin_nontemporal_load(ap + 2);
    i32x4 v3 = __builtin_nontemporal_load(ap + 3);
    i32x4 v4 = __builtin_nontemporal_load(ap + 4);
    i32x4 v5 = __builtin_nontemporal_load(ap + 5);
    i32x4 v6 = __builtin_nontemporal_load(ap + 6);
    i32x4 v7 = __builtin_nontemporal_load(ap + 7);
    unsigned word = 0;
#pragma unroll
    for (int j = 0; j < 4; ++j) {
      word |= ((unsigned)(v0[j] != 0)) << (0 + j);
      word |= ((unsigned)(v1[j] != 0)) << (4 + j);
      word |= ((unsigned)(v2[j] != 0)) << (8 + j);
      word |= ((unsigned)(v3[j] != 0)) << (12 + j);
      word |= ((unsigned)(v4[j] != 0)) << (16 + j);
      word |= ((unsigned)(v5[j] != 0)) << (20 + j);
      word |= ((unsigned)(v6[j] != 0)) << (24 + j);
      word |= ((unsigned)(v7[j] != 0)) << (28 + j);
    }
    mb[gid] = word;
    return;
  }
  int blk = blockIdx.x;                // 0..511 proj1, 16 rows each
  int rowg = blk * 16;
  int b = rowg >> 11, rloc = rowg & (NN - 1);
  int tid = threadIdx.x, lane = tid & 63, h = tid >> 6;
  int cl = lane & 15, g = lane >> 4;

  const float* xr = x + (size_t)(rowg + cl) * 64 + 8 * g;
  bf16x8 af[2];
#pragma unroll
  for (int ks = 0; ks < 2; ++ks)
    af[ks] = cvt8(*(const f32x4*)(xr + ks * 32), *(const f32x4*)(xr + ks * 32 + 4));

  f32x4 zero = {0.f, 0.f, 0.f, 0.f};
  f32x4 acc[4] = {zero, zero, zero, zero};
#pragma unroll
  for (int ft = 0; ft < 4; ++ft) {
    const float* wr = W1 + (size_t)(h * 64 + ft * 16 + cl) * 64 + 8 * g;
#pragma unroll
    for (int ks = 0; ks < 2; ++ks) {
      bf16x8 bfr = cvt8(*(const f32x4*)(wr + ks * 32), *(const f32x4*)(wr + ks * 32 + 4));
      acc[ft] = __builtin_amdgcn_mfma_f32_16x16x32_bf16(af[ks], bfr, acc[ft], 0, 0, 0);
    }
  }
  // fragment-layout store: node J = rloc+4g+r, feat F = ft*16+cl
  unsigned short* bhb = wht1 + (size_t)(b * NH + h) * 64 * NN;
  int kb = rloc >> 5;
  int gd = ((rloc >> 3) & 2) + (g >> 1);
  int e0 = 4 * (g & 1);
  float ps[4] = {0.f, 0.f, 0.f, 0.f}, pd[4] = {0.f, 0.f, 0.f, 0.f};
#pragma unroll
  for (int ft = 0; ft < 4; ++ft) {
    float as = a1[h * 128 + ft * 16 + cl];
    float ad = a1[h * 128 + 64 + ft * 16 + cl];
    u16x4 w4;
#pragma unroll
    for (int r = 0; r < 4; ++r) {
      float v = acc[ft][r];
      w4[r] = f2bf1(v);
      ps[r] += v * as; pd[r] += v * ad;
    }
    *(u16x4*)(bhb + (size_t)(kb * 4 + ft) * 512 + cl * 8 + gd * 128 + e0) = w4;
  }
#pragma unroll
  for (int r = 0; r < 4; ++r) {
    float s = ps[r], d = pd[r];
    s += __shfl_xor(s, 1); s += __shfl_xor(s, 2); s += __shfl_xor(s, 4); s += __shfl_xor(s, 8);
    d += __shfl_xor(d, 1); d += __shfl_xor(d, 2); d += __shfl_xor(d, 4); d += __shfl_xor(d, 8);
    if (cl == 0) {
      int idx = (b * NH + h) * NN + rloc + 4 * g + r;
      ssrc1[idx] = s;
      G1g[idx] = __expf(d);
      G2g[idx] = __expf(0.2f * d);
    }
  }
}

// ---------- k2: layer-1 attention. bid=[tile(5)][bh(4)] -> XCD pinned per (b,h)
// block = 64 rows; 8 waves = 2 row-pair-tiles (32 rows) x 4 j-quarters
// each wave: 2 P-frags per B-frag load -> half the L2 fragment traffic
__global__ __launch_bounds__(512, 4) void k2_attn1(
    const unsigned short* __restrict__ wht1, const float* __restrict__ ssrc1,
    const float* __restrict__ G1g, const float* __restrict__ G2g,
    const unsigned* __restrict__ mb, unsigned short* __restrict__ hout) {
  // phase 1: sdm[64][65] 16640 B | sG1 8 KB | sG2 8 KB = 33024 B
  // phase 2 (overlay): cmb[3][2][32][68] 52224 B + sden[3][2][32] 768 B = 52992 B
  __shared__ __align__(16) char smem[53248];
  __shared__ float swmax[8];
  unsigned (*sdm)[65] = (unsigned(*)[65])smem;
  float* sG1 = (float*)(smem + 16640);
  float* sG2 = (float*)(smem + 16640 + 8192);
  float (*cmb)[2][32][68] = (float(*)[2][32][68])smem;
  float (*sden)[2][32] = (float(*)[2][32])(smem + 52224);

  int bid = blockIdx.x;                // 512 = [tile(5 bits hi)][bh(4 bits lo)]
  int bh = bid & 15, tile = bid >> 4;  // bid%8 = bh%8 -> same XCD per (b,h)
  int b = bh >> 2, h = bh & 3;
  int rowblk = tile << 6;
  int t = threadIdx.x, lane = t & 63, w = t >> 6;
  int rt = w & 1, jh = w >> 1;         // row-pair-tile, j-quarter
  int cl = lane & 15, g = lane >> 4, g8 = g * 8;
  int rbase = rt * 32;

  { // stage 64 rows x 64 mask words (8 words per thread)
    int row = t >> 3, c = (t & 7) * 8;
    const unsigned* mrow = mb + (size_t)(b * NN + rowblk + row) * NW + c;
    uint4 v0 = *(const uint4*)(mrow);
    uint4 v1 = *(const uint4*)(mrow + 4);
    sdm[row][c + 0] = v0.x; sdm[row][c + 1] = v0.y;
    sdm[row][c + 2] = v0.z; sdm[row][c + 3] = v0.w;
    sdm[row][c + 4] = v1.x; sdm[row][c + 5] = v1.y;
    sdm[row][c + 6] = v1.z; sdm[row][c + 7] = v1.w;
  }
  { // stage G1/G2 (2048 floats each) + block-local max of G1
    const f32x4* g1p = (const f32x4*)(G1g + (size_t)(b * NH + h) * NN);
    const f32x4* g2p = (const f32x4*)(G2g + (size_t)(b * NH + h) * NN);
    f32x4 gv = g1p[t];
    ((f32x4*)sG1)[t] = gv;
    ((f32x4*)sG2)[t] = g2p[t];
    float gmx = fmaxf(fmaxf(gv[0], gv[1]), fmaxf(gv[2], gv[3]));
    gmx = fmaxf(gmx, __shfl_xor(gmx, 1));  gmx = fmaxf(gmx, __shfl_xor(gmx, 2));
    gmx = fmaxf(gmx, __shfl_xor(gmx, 4));  gmx = fmaxf(gmx, __shfl_xor(gmx, 8));
    gmx = fmaxf(gmx, __shfl_xor(gmx, 16)); gmx = fmaxf(gmx, __shfl_xor(gmx, 32));
    if (lane == 0) swmax[w] = gmx;
  }
  size_t sbase = (size_t)(b * NH + h) * NN + rowblk + rbase;
  float s0 = ssrc1[sbase + cl];
  float s1 = ssrc1[sbase + 16 + cl];
  __syncthreads();
  float mxv = fmaxf(fmaxf(fmaxf(swmax[0], swmax[1]), fmaxf(swmax[2], swmax[3])),
                    fmaxf(fmaxf(swmax[4], swmax[5]), fmaxf(swmax[6], swmax[7])));
  float logMx = __logf(mxv);
  float m0 = lrelu(s0 + logMx), m1 = lrelu(s1 + logMx);
  float F10 = __expf(s0 - m0), F20 = __expf(0.2f * s0 - m0);
  float F11 = __expf(s1 - m1), F21 = __expf(0.2f * s1 - m1);

  short onev = (cl == 0) ? (short)0x3F80 : (short)0;
  bf16x8 ones = {onev, onev, onev, onev, onev, onev, onev, onev};
  f32x4 zero = {0.f, 0.f, 0.f, 0.f};
  f32x4 acc[2][4] = {{zero, zero, zero, zero}, {zero, zero, zero, zero}};
  f32x4 accd[2] = {zero, zero};        // denominators via ones column
  const unsigned short* fbase = wht1 + (size_t)(b * NH + h) * 64 * NN + lane * 8;
  int kb0 = jh * 16;

  bf16x8 curf[4], nxtf[4];
#pragma unroll
  for (int ft = 0; ft < 4; ++ft)
    curf[ft] = *(const bf16x8*)(fbase + (size_t)(kb0 * 4 + ft) * 512);

  for (int i = 0; i < 16; ++i) {
    int kb = kb0 + i;
    if (i < 15) {                      // prefetch next iteration's fragments
#pragma unroll
      for (int ft = 0; ft < 4; ++ft)
        nxtf[ft] = *(const bf16x8*)(fbase + (size_t)((kb + 1) * 4 + ft) * 512);
    }
    unsigned by0 = (sdm[rbase + cl][kb] >> g8) & 0xFFu;
    unsigned by1 = (sdm[rbase + 16 + cl][kb] >> g8) & 0xFFu;
    int j0 = kb * 32 + g8;
    f32x4 g1a = *(const f32x4*)(sG1 + j0);
    f32x4 g1b = *(const f32x4*)(sG1 + j0 + 4);
    f32x4 g2a = *(const f32x4*)(sG2 + j0);
    f32x4 g2b = *(const f32x4*)(sG2 + j0 + 4);
    float wv0[8], wv1[8];
#pragma unroll
    for (int e = 0; e < 8; ++e) {
      float g1 = (e < 4) ? g1a[e] : g1b[e - 4];
      float g2 = (e < 4) ? g2a[e] : g2b[e - 4];
      float v0 = fmaxf(F10 * g1, F20 * g2);   // exp(lrelu(s+t)-m), branch-free
      float v1 = fmaxf(F11 * g1, F21 * g2);
      wv0[e] = ((by0 >> e) & 1u) ? v0 : 0.f;
      wv1[e] = ((by1 >> e) & 1u) ? v1 : 0.f;
    }
    union { unsigned u[4]; bf16x8 v; } pa0, pa1;
    pa0.u[0] = pk2(wv0[0], wv0[1]); pa0.u[1] = pk2(wv0[2], wv0[3]);
    pa0.u[2] = pk2(wv0[4], wv0[5]); pa0.u[3] = pk2(wv0[6], wv0[7]);
    pa1.u[0] = pk2(wv1[0], wv1[1]); pa1.u[1] = pk2(wv1[2], wv1[3]);
    pa1.u[2] = pk2(wv1[4], wv1[5]); pa1.u[3] = pk2(wv1[6], wv1[7]);
#pragma unroll
    for (int ft = 0; ft < 4; ++ft) {
      acc[0][ft] = __builtin_amdgcn_mfma_f32_16x16x32_bf16(pa0.v, curf[ft], acc[0][ft], 0, 0, 0);
      acc[1][ft] = __builtin_amdgcn_mfma_f32_16x16x32_bf16(pa1.v, curf[ft], acc[1][ft], 0, 0, 0);
    }
    accd[0] = __builtin_amdgcn_mfma_f32_16x16x32_bf16(pa0.v, ones, accd[0], 0, 0, 0);
    accd[1] = __builtin_amdgcn_mfma_f32_16x16x32_bf16(pa1.v, ones, accd[1], 0, 0, 0);
#pragma unroll
    for (int ft = 0; ft < 4; ++ft) curf[ft] = nxtf[ft];
  }
  __syncthreads();                     // all phase-1 LDS reads done; overlay safe
  if (jh > 0) {
    int p = jh - 1;
#pragma unroll
    for (int f = 0; f < 2; ++f) {
#pragma unroll
      for (int ft = 0; ft < 4; ++ft)
#pragma unroll
        for (int r = 0; r < 4; ++r)
          cmb[p][rt][f * 16 + 4 * g + r][ft * 16 + cl] = acc[f][ft][r];
      if (cl == 0) {
#pragma unroll
        for (int r = 0; r < 4; ++r) sden[p][rt][f * 16 + 4 * g + r] = accd[f][r];
      }
    }
  }
  __syncthreads();
  if (jh == 0) {
#pragma unroll
    for (int f = 0; f < 2; ++f) {
#pragma unroll
      for (int r = 0; r < 4; ++r) {
        int rloc32 = f * 16 + 4 * g + r;
        float dself = __shfl(accd[f][r], lane & 48);   // denom col 0 at cl==0
        float den = dself + sden[0][rt][rloc32] + sden[1][rt][rloc32] + sden[2][rt][rloc32];
        float inv = 1.f / den;
        int row = rowblk + rbase + rloc32;
        unsigned short* dst = hout + (size_t)(b * NN + row) * 256 + h * 64;
#pragma unroll
        for (int ft = 0; ft < 4; ++ft) {
          float v = acc[f][ft][r] + cmb[0][rt][rloc32][ft * 16 + cl] +
                    cmb[1][rt][rloc32][ft * 16 + cl] + cmb[2][rt][rloc32][ft * 16 + cl];
          v *= inv;
          v = v > 0.f ? v : (__expf(v) - 1.f);      // ELU
          dst[ft * 16 + cl] = f2bf1(v);             // bf16 (k3 rounds here anyway)
        }
      }
    }
  }
}

// ---------- k3: Wh2 = h @ W2^T via MFMA split-K; frag-layout store + scores ----
__global__ __launch_bounds__(256) void k3_proj2(
    const unsigned short* __restrict__ hin, const float* __restrict__ W2,
    const float* __restrict__ a2, unsigned short* __restrict__ wh2t,
    float* __restrict__ ssrc2, float* __restrict__ G1o, float* __restrict__ G2o) {
  __shared__ float cmb[4][16][33];
  int blk = blockIdx.x;                 // 512: 16 rows each
  int b = blk >> 7, rowbase = (blk & 127) << 4;
  int t = threadIdx.x, lane = t & 63, w = t >> 6;
  int cl = lane & 15, g = lane >> 4;
  int k0 = w * 64;                      // K split across 4 waves

  const unsigned short* hr = hin + (size_t)(b * NN + rowbase + cl) * 256 + k0 + 8 * g;
  bf16x8 af[2];
#pragma unroll
  for (int ks = 0; ks < 2; ++ks)
    af[ks] = *(const bf16x8*)(hr + ks * 32);       // bf16 direct A-fragment

  f32x4 zero = {0.f, 0.f, 0.f, 0.f};
  f32x4 acc[2] = {zero, zero};
#pragma unroll
  for (int ft = 0; ft < 2; ++ft) {
    const float* wr = W2 + (size_t)(ft * 16 + cl) * 256 + k0 + 8 * g;
#pragma unroll
    for (int ks = 0; ks < 2; ++ks) {
      bf16x8 bfr = cvt8(*(const f32x4*)(wr + ks * 32), *(const f32x4*)(wr + ks * 32 + 4));
      acc[ft] = __builtin_amdgcn_mfma_f32_16x16x32_bf16(af[ks], bfr, acc[ft], 0, 0, 0);
    }
  }
#pragma unroll
  for (int ft = 0; ft < 2; ++ft)
#pragma unroll
    for (int r = 0; r < 4; ++r)
      cmb[w][4 * g + r][ft * 16 + cl] = acc[ft][r];
  __syncthreads();

  int row = t >> 4, c0 = t & 15;
  float v0 = cmb[0][row][c0] + cmb[1][row][c0] + cmb[2][row][c0] + cmb[3][row][c0];
  float v1 = cmb[0][row][c0 + 16] + cmb[1][row][c0 + 16] + cmb[2][row][c0 + 16] + cmb[3][row][c0 + 16];
  float ps = v0 * a2[c0] + v1 * a2[c0 + 16];
  float pd = v0 * a2[32 + c0] + v1 * a2[32 + c0 + 16];
  ps += __shfl_xor(ps, 1); ps += __shfl_xor(ps, 2); ps += __shfl_xor(ps, 4); ps += __shfl_xor(ps, 8);
  pd += __shfl_xor(pd, 1); pd += __shfl_xor(pd, 2); pd += __shfl_xor(pd, 4); pd += __shfl_xor(pd, 8);
  if (c0 == 0) {
    int idx = b * NN + rowbase + row;
    ssrc2[idx] = ps;
    G1o[idx] = __expf(pd);
    G2o[idx] = __expf(0.2f * pd);
  }
  cmb[0][row][c0] = v0;
  cmb[0][row][c0 + 16] = v1;
  __syncthreads();
  // fragment-layout bf16 store: feat = col, nodes J = rowbase + 2*rg + {0,1}
  int col = t >> 3, rg = t & 7;
  unsigned pk = pk2(cmb[0][2 * rg][col], cmb[0][2 * rg + 1][col]);
  int kb2 = rowbase >> 5;
  int gd = ((rowbase >> 3) & 2) + (rg >> 2);
  size_t off = (size_t)(kb2 * 2 + (col >> 4)) * 512 + (col & 15) * 8 + gd * 128 + 2 * (rg & 3);
  *(unsigned*)(wh2t + (size_t)b * 32 * NN + off) = pk;
}

// ---------- k4: layer-2 attention. block = 32 rows; 8 waves = 2 rowtiles x 4 jq
__global__ __launch_bounds__(512) void k4_attn2(
    const unsigned short* __restrict__ wh2t, const float* __restrict__ ssrc2,
    const float* __restrict__ G1o, const float* __restrict__ G2o,
    const unsigned* __restrict__ mb, float* __restrict__ outp) {
  // phase 1: sdm[32][65] 8320 B | sG1 8 KB | sG2 8 KB = 24704 B
  // phase 2 (overlay): cmb[3][2][16][36] 13824 B + sden[3][2][16] 384 B
  __shared__ __align__(16) char smem[24704];
  __shared__ float swmax[8];
  unsigned (*sdm)[65] = (unsigned(*)[65])smem;
  float* sG1 = (float*)(smem + 8320);
  float* sG2 = (float*)(smem + 8320 + 8192);
  float (*cmb)[2][16][36] = (float(*)[2][16][36])smem;
  float (*sden)[2][16] = (float(*)[2][16])(smem + 13824);

  int bid = blockIdx.x;                // 256 = [tile(6 hi)][b(2 lo)]
  int b = bid & 3, tile = bid >> 2;
  int rowblk = tile << 5;
  int t = threadIdx.x, lane = t & 63, w = t >> 6;
  int wloc = w & 1, jh = w >> 1;       // rowtile, j-quarter
  int cl = lane & 15, g = lane >> 4, g8 = g * 8;

  { // stage 32 rows x 64 mask words (4 per thread)
    int row = t >> 4, c = (t & 15) * 4;
    uint4 v = *(const uint4*)(mb + (size_t)(b * NN + rowblk + row) * NW + c);
    sdm[row][c + 0] = v.x; sdm[row][c + 1] = v.y;
    sdm[row][c + 2] = v.z; sdm[row][c + 3] = v.w;
  }
  { // stage G + block-local max of G1
    f32x4 gv = ((const f32x4*)(G1o + (size_t)b * NN))[t];
    ((f32x4*)sG1)[t] = gv;
    ((f32x4*)sG2)[t] = ((const f32x4*)(G2o + (size_t)b * NN))[t];
    float gmx = fmaxf(fmaxf(gv[0], gv[1]), fmaxf(gv[2], gv[3]));
    gmx = fmaxf(gmx, __shfl_xor(gmx, 1));  gmx = fmaxf(gmx, __shfl_xor(gmx, 2));
    gmx = fmaxf(gmx, __shfl_xor(gmx, 4));  gmx = fmaxf(gmx, __shfl_xor(gmx, 8));
    gmx = fmaxf(gmx, __shfl_xor(gmx, 16)); gmx = fmaxf(gmx, __shfl_xor(gmx, 32));
    if (lane == 0) swmax[w] = gmx;
  }
  int rowW = rowblk + wloc * 16;
  float s = ssrc2[b * NN + rowW + cl];
  __syncthreads();
  float mxv = fmaxf(fmaxf(fmaxf(swmax[0], swmax[1]), fmaxf(swmax[2], swmax[3])),
                    fmaxf(fmaxf(swmax[4], swmax[5]), fmaxf(swmax[6], swmax[7])));
  float logMx = __logf(mxv);
  float m = lrelu(s + logMx);
  float F1 = __expf(s - m), F2 = __expf(0.2f * s - m);

  short onev = (cl == 0) ? (short)0x3F80 : (short)0;
  bf16x8 ones = {onev, onev, onev, onev, onev, onev, onev, onev};
  f32x4 zero = {0.f, 0.f, 0.f, 0.f};
  f32x4 acc[2] = {zero, zero};
  f32x4 acc1 = zero;
  const unsigned short* fbase = wh2t + (size_t)b * 32 * NN + lane * 8;
  int rloc = wloc * 16 + cl;
  int kb0 = jh * 16;

  bf16x8 curf[2], nxtf[2];
#pragma unroll
  for (int ft = 0; ft < 2; ++ft)
    curf[ft] = *(const bf16x8*)(fbase + (size_t)(kb0 * 2 + ft) * 512);

  for (int i = 0; i < 16; ++i) {
    int kb = kb0 + i;
    if (i < 15) {
#pragma unroll
      for (int ft = 0; ft < 2; ++ft)
        nxtf[ft] = *(const bf16x8*)(fbase + (size_t)((kb + 1) * 2 + ft) * 512);
    }
    unsigned by = (sdm[rloc][kb] >> g8) & 0xFFu;
    int j0 = kb * 32 + g8;
    f32x4 g1a = *(const f32x4*)(sG1 + j0);
    f32x4 g1b = *(const f32x4*)(sG1 + j0 + 4);
    f32x4 g2a = *(const f32x4*)(sG2 + j0);
    f32x4 g2b = *(const f32x4*)(sG2 + j0 + 4);
    float wv[8];
#pragma unroll
    for (int e = 0; e < 8; ++e) {
      float g1 = (e < 4) ? g1a[e] : g1b[e - 4];
      float g2 = (e < 4) ? g2a[e] : g2b[e - 4];
      float v = fmaxf(F1 * g1, F2 * g2);
      wv[e] = ((by >> e) & 1u) ? v : 0.f;
    }
    union { unsigned u[4]; bf16x8 v; } pa;
    pa.u[0] = pk2(wv[0], wv[1]); pa.u[1] = pk2(wv[2], wv[3]);
    pa.u[2] = pk2(wv[4], wv[5]); pa.u[3] = pk2(wv[6], wv[7]);
#pragma unroll
    for (int ft = 0; ft < 2; ++ft)
      acc[ft] = __builtin_amdgcn_mfma_f32_16x16x32_bf16(pa.v, curf[ft], acc[ft], 0, 0, 0);
    acc1 = __builtin_amdgcn_mfma_f32_16x16x32_bf16(pa.v, ones, acc1, 0, 0, 0);
#pragma unroll
    for (int ft = 0; ft < 2; ++ft) curf[ft] = nxtf[ft];
  }
  __syncthreads();                     // all LDS reads done; overlay safe
  if (jh > 0) {
#pragma unroll
    for (int ft = 0; ft < 2; ++ft)
#pragma unroll
      for (int r = 0; r < 4; ++r)
        cmb[jh - 1][wloc][4 * g + r][ft * 16 + cl] = acc[ft][r];
    if (cl == 0) {
#pragma unroll
      for (int r = 0; r < 4; ++r) sden[jh - 1][wloc][4 * g + r] = acc1[r];
    }
  }
  __syncthreads();
  if (jh == 0) {
#pragma unroll
    for (int r = 0; r < 4; ++r) {
      int rowm = 4 * g + r;
      float dself = __shfl(acc1[r], lane & 48);
      float den = dself + sden[0][wloc][rowm] + sden[1][wloc][rowm] + sden[2][wloc][rowm];
      float inv = 1.f / den;
      float* dst = outp + (size_t)(b * NN + rowW + rowm) * 32;
#pragma unroll
      for (int ft = 0; ft < 2; ++ft) {
        float v = acc[ft][r] + cmb[0][wloc][rowm][ft * 16 + cl] +
                  cmb[1][wloc][rowm][ft * 16 + cl] + cmb[2][wloc][rowm][ft * 16 + cl];
        dst[ft * 16 + cl] = v * inv;
      }
    }
  }
}

extern "C" void kernel_launch(void* const* d_in, const int* in_sizes, int n_in,
                              void* d_out, int out_size, void* d_ws, size_t ws_size,
                              hipStream_t stream) {
  (void)in_sizes; (void)n_in; (void)out_size; (void)ws_size;
  const float* x   = (const float*)d_in[0];
  const int*   adj = (const int*)d_in[1];
  const float* W1  = (const float*)d_in[2];
  const float* a1  = (const float*)d_in[3];
  const float* W2  = (const float*)d_in[4];
  const float* a2  = (const float*)d_in[5];
  float* outp = (float*)d_out;
  char* ws = (char*)d_ws;

  unsigned*       mbits = (unsigned*)(ws);                                   // 2 MB
  unsigned short* wht1  = (unsigned short*)(ws + (size_t)(2u << 20));        // 4 MB
  float*          ssrc1 = (float*)(ws + (size_t)(6u << 20));                 // 128 KB
  float*          G1g   = (float*)(ws + (size_t)(6u << 20) + (128u << 10));  // 128 KB
  float*          G2g   = (float*)(ws + (size_t)(6u << 20) + (256u << 10));  // 128 KB
  unsigned short* hbuf  = (unsigned short*)(ws + (size_t)(6u << 20) + (512u << 10)); // 4 MB bf16
  unsigned short* wh2t  = (unsigned short*)(ws + (size_t)(14u << 20) + (512u << 10)); // 512 KB
  float*          ssrc2 = (float*)(ws + (size_t)(15u << 20));                // 32 KB
  float*          G1o   = (float*)(ws + (size_t)(15u << 20) + (32u << 10));  // 32 KB
  float*          G2o   = (float*)(ws + (size_t)(15u << 20) + (64u << 10));  // 32 KB

  kA      <<<2560, 256, 0, stream>>>(adj, mbits, x, W1, a1, wht1, ssrc1, G1g, G2g);
  k2_attn1<<<512,  512, 0, stream>>>(wht1, ssrc1, G1g, G2g, mbits, hbuf);
  k3_proj2<<<512,  256, 0, stream>>>(hbuf, W2, a2, wh2t, ssrc2, G1o, G2o);
  k4_attn2<<<256,  512, 0, stream>>>(wh2t, ssrc2, G1o, G2o, mbits, outp);
}

// Round 10
// 163.271 us; speedup vs baseline: 1.2188x; 1.0096x over previous
//
#include <hip/hip_runtime.h>
#include <hip/hip_bf16.h>
#include <cstdint>

#define NN 2048
#define NH 4
#define NW 64   // mask words per row

typedef __attribute__((ext_vector_type(8))) short bf16x8;
typedef __attribute__((ext_vector_type(4))) float f32x4;
typedef __attribute__((ext_vector_type(4))) int i32x4;
typedef __attribute__((ext_vector_type(4))) unsigned short u16x4;

__device__ __forceinline__ float lrelu(float s) { return s > 0.f ? s : 0.2f * s; }

__device__ __forceinline__ unsigned pk2(float lo, float hi) {
  __hip_bfloat162 h2 = __float22bfloat162_rn(make_float2(lo, hi));
  union { __hip_bfloat162 h; unsigned u; } c; c.h = h2; return c.u;
}
__device__ __forceinline__ unsigned short f2bf1(float f) {
  __hip_bfloat16 h = __float2bfloat16(f);
  union { __hip_bfloat16 h; unsigned short u; } c; c.h = h; return c.u;
}
__device__ __forceinline__ bf16x8 cvt8(f32x4 v0, f32x4 v1) {
  union { unsigned u[4]; bf16x8 v; } r;
  r.u[0] = pk2(v0[0], v0[1]); r.u[1] = pk2(v0[2], v0[3]);
  r.u[2] = pk2(v1[0], v1[1]); r.u[3] = pk2(v1[2], v1[3]);
  return r.v;
}

// Fragment layout for Wh^T (per (b,h) slab of F feats x 2048 nodes):
// short index = (kb*FT + ft)*512 + (feat&15)*8 + gd*128 + e  with node = kb*32+8*gd+e
// -> k-attn lane `lane` loads 16B at frag_base + (kb*FT+ft)*512 + lane*8
//    holding feat = ft*16 + (lane&15), nodes = kb*32 + (lane>>4)*8 .. +7 (B-frag order)

// ---------- kA: blocks [0,512): proj1; [512,2560): pack (32 ints -> 1 word/thr)
__global__ __launch_bounds__(256) void kA(
    const int* __restrict__ adj, unsigned* __restrict__ mb,
    const float* __restrict__ x, const float* __restrict__ W1,
    const float* __restrict__ a1, unsigned short* __restrict__ wht1,
    float* __restrict__ ssrc1, float* __restrict__ G1g, float* __restrict__ G2g) {
  if (blockIdx.x >= 512) {
    size_t gid = (size_t)(blockIdx.x - 512) * 256 + threadIdx.x;  // word index
    const i32x4* ap = (const i32x4*)adj + gid * 8;
    i32x4 v0 = __builtin_nontemporal_load(ap + 0);
    i32x4 v1 = __builtin_nontemporal_load(ap + 1);
    i32x4 v2 = __builtin_nontemporal_load(ap + 2);
    i32x4 v3 = __builtin_nontemporal_load(ap + 3);
    i32x4 v4 = __builtin_nontemporal_load(ap + 4);
    i32x4 v5 = __builtin_nontemporal_load(ap + 5);
    i32x4 v6 = __builtin_nontemporal_load(ap + 6);
    i32x4 v7 = __builtin_nontemporal_load(ap + 7);
    unsigned word = 0;
#pragma unroll
    for (int j = 0; j < 4; ++j) {
      word |= ((unsigned)(v0[j] != 0)) << (0 + j);
      word |= ((unsigned)(v1[j] != 0)) << (4 + j);
      word |= ((unsigned)(v2[j] != 0)) << (8 + j);
      word |= ((unsigned)(v3[j] != 0)) << (12 + j);
      word |= ((unsigned)(v4[j] != 0)) << (16 + j);
      word |= ((unsigned)(v5[j] != 0)) << (20 + j);
      word |= ((unsigned)(v6[j] != 0)) << (24 + j);
      word |= ((unsigned)(v7[j] != 0)) << (28 + j);
    }
    mb[gid] = word;
    return;
  }
  int blk = blockIdx.x;                // 0..511 proj1, 16 rows each
  int rowg = blk * 16;
  int b = rowg >> 11, rloc = rowg & (NN - 1);
  int tid = threadIdx.x, lane = tid & 63, h = tid >> 6;
  int cl = lane & 15, g = lane >> 4;

  const float* xr = x + (size_t)(rowg + cl) * 64 + 8 * g;
  bf16x8 af[2];
#pragma unroll
  for (int ks = 0; ks < 2; ++ks)
    af[ks] = cvt8(*(const f32x4*)(xr + ks * 32), *(const f32x4*)(xr + ks * 32 + 4));

  f32x4 zero = {0.f, 0.f, 0.f, 0.f};
  f32x4 acc[4] = {zero, zero, zero, zero};
#pragma unroll
  for (int ft = 0; ft < 4; ++ft) {
    const float* wr = W1 + (size_t)(h * 64 + ft * 16 + cl) * 64 + 8 * g;
#pragma unroll
    for (int ks = 0; ks < 2; ++ks) {
      bf16x8 bfr = cvt8(*(const f32x4*)(wr + ks * 32), *(const f32x4*)(wr + ks * 32 + 4));
      acc[ft] = __builtin_amdgcn_mfma_f32_16x16x32_bf16(af[ks], bfr, acc[ft], 0, 0, 0);
    }
  }
  // fragment-layout store: node J = rloc+4g+r, feat F = ft*16+cl
  unsigned short* bhb = wht1 + (size_t)(b * NH + h) * 64 * NN;
  int kb = rloc >> 5;
  int gd = ((rloc >> 3) & 2) + (g >> 1);
  int e0 = 4 * (g & 1);
  float ps[4] = {0.f, 0.f, 0.f, 0.f}, pd[4] = {0.f, 0.f, 0.f, 0.f};
#pragma unroll
  for (int ft = 0; ft < 4; ++ft) {
    float as = a1[h * 128 + ft * 16 + cl];
    float ad = a1[h * 128 + 64 + ft * 16 + cl];
    u16x4 w4;
#pragma unroll
    for (int r = 0; r < 4; ++r) {
      float v = acc[ft][r];
      w4[r] = f2bf1(v);
      ps[r] += v * as; pd[r] += v * ad;
    }
    *(u16x4*)(bhb + (size_t)(kb * 4 + ft) * 512 + cl * 8 + gd * 128 + e0) = w4;
  }
#pragma unroll
  for (int r = 0; r < 4; ++r) {
    float s = ps[r], d = pd[r];
    s += __shfl_xor(s, 1); s += __shfl_xor(s, 2); s += __shfl_xor(s, 4); s += __shfl_xor(s, 8);
    d += __shfl_xor(d, 1); d += __shfl_xor(d, 2); d += __shfl_xor(d, 4); d += __shfl_xor(d, 8);
    if (cl == 0) {
      int idx = (b * NH + h) * NN + rloc + 4 * g + r;
      ssrc1[idx] = s;
      G1g[idx] = __expf(d);
      G2g[idx] = __expf(0.2f * d);
    }
  }
}

// ---------- k2: layer-1 attention. bid=[tile(5)][bh(4)] -> XCD pinned per (b,h)
// block = 64 rows; 8 waves = 2 row-pair-tiles (32 rows) x 4 j-quarters
__global__ __launch_bounds__(512, 4) void k2_attn1(
    const unsigned short* __restrict__ wht1, const float* __restrict__ ssrc1,
    const float* __restrict__ G1g, const float* __restrict__ G2g,
    const unsigned* __restrict__ mb, unsigned short* __restrict__ hout) {
  // phase 1: sdm[64][65] 16640 B | sG1 8 KB | sG2 8 KB = 33024 B
  // phase 2 (overlay): cmb[3][2][32][68] 52224 B + sden[3][2][32] 768 B = 52992 B
  __shared__ __align__(16) char smem[53248];
  __shared__ float swmax[8];
  unsigned (*sdm)[65] = (unsigned(*)[65])smem;
  float* sG1 = (float*)(smem + 16640);
  float* sG2 = (float*)(smem + 16640 + 8192);
  float (*cmb)[2][32][68] = (float(*)[2][32][68])smem;
  float (*sden)[2][32] = (float(*)[2][32])(smem + 52224);

  int bid = blockIdx.x;                // 512 = [tile(5 bits hi)][bh(4 bits lo)]
  int bh = bid & 15, tile = bid >> 4;  // bid%8 = bh%8 -> same XCD per (b,h)
  int b = bh >> 2, h = bh & 3;
  int rowblk = tile << 6;
  int t = threadIdx.x, lane = t & 63, w = t >> 6;
  int rt = w & 1, jh = w >> 1;         // row-pair-tile, j-quarter
  int cl = lane & 15, g = lane >> 4, g8 = g * 8;
  int rbase = rt * 32;

  { // stage 64 rows x 64 mask words (8 words per thread)
    int row = t >> 3, c = (t & 7) * 8;
    const unsigned* mrow = mb + (size_t)(b * NN + rowblk + row) * NW + c;
    uint4 v0 = *(const uint4*)(mrow);
    uint4 v1 = *(const uint4*)(mrow + 4);
    sdm[row][c + 0] = v0.x; sdm[row][c + 1] = v0.y;
    sdm[row][c + 2] = v0.z; sdm[row][c + 3] = v0.w;
    sdm[row][c + 4] = v1.x; sdm[row][c + 5] = v1.y;
    sdm[row][c + 6] = v1.z; sdm[row][c + 7] = v1.w;
  }
  { // stage G1/G2 (2048 floats each) + block-local max of G1
    const f32x4* g1p = (const f32x4*)(G1g + (size_t)(b * NH + h) * NN);
    const f32x4* g2p = (const f32x4*)(G2g + (size_t)(b * NH + h) * NN);
    f32x4 gv = g1p[t];
    ((f32x4*)sG1)[t] = gv;
    ((f32x4*)sG2)[t] = g2p[t];
    float gmx = fmaxf(fmaxf(gv[0], gv[1]), fmaxf(gv[2], gv[3]));
    gmx = fmaxf(gmx, __shfl_xor(gmx, 1));  gmx = fmaxf(gmx, __shfl_xor(gmx, 2));
    gmx = fmaxf(gmx, __shfl_xor(gmx, 4));  gmx = fmaxf(gmx, __shfl_xor(gmx, 8));
    gmx = fmaxf(gmx, __shfl_xor(gmx, 16)); gmx = fmaxf(gmx, __shfl_xor(gmx, 32));
    if (lane == 0) swmax[w] = gmx;
  }
  size_t sbase = (size_t)(b * NH + h) * NN + rowblk + rbase;
  float s0 = ssrc1[sbase + cl];
  float s1 = ssrc1[sbase + 16 + cl];
  __syncthreads();
  float mxv = fmaxf(fmaxf(fmaxf(swmax[0], swmax[1]), fmaxf(swmax[2], swmax[3])),
                    fmaxf(fmaxf(swmax[4], swmax[5]), fmaxf(swmax[6], swmax[7])));
  float logMx = __logf(mxv);
  float m0 = lrelu(s0 + logMx), m1 = lrelu(s1 + logMx);
  float F10 = __expf(s0 - m0), F20 = __expf(0.2f * s0 - m0);
  float F11 = __expf(s1 - m1), F21 = __expf(0.2f * s1 - m1);

  short onev = (cl == 0) ? (short)0x3F80 : (short)0;
  bf16x8 ones = {onev, onev, onev, onev, onev, onev, onev, onev};
  f32x4 zero = {0.f, 0.f, 0.f, 0.f};
  f32x4 acc[2][4] = {{zero, zero, zero, zero}, {zero, zero, zero, zero}};
  f32x4 accd[2] = {zero, zero};        // denominators via ones column
  const unsigned short* fbase = wht1 + (size_t)(b * NH + h) * 64 * NN + lane * 8;
  int kb0 = jh * 16;

  bf16x8 curf[4], nxtf[4];
#pragma unroll
  for (int ft = 0; ft < 4; ++ft)
    curf[ft] = *(const bf16x8*)(fbase + (size_t)(kb0 * 4 + ft) * 512);

  for (int i = 0; i < 16; ++i) {
    int kb = kb0 + i;
    if (i < 15) {                      // prefetch next iteration's fragments
#pragma unroll
      for (int ft = 0; ft < 4; ++ft)
        nxtf[ft] = *(const bf16x8*)(fbase + (size_t)((kb + 1) * 4 + ft) * 512);
    }
    unsigned by0 = (sdm[rbase + cl][kb] >> g8) & 0xFFu;
    unsigned by1 = (sdm[rbase + 16 + cl][kb] >> g8) & 0xFFu;
    int j0 = kb * 32 + g8;
    f32x4 g1a = *(const f32x4*)(sG1 + j0);
    f32x4 g1b = *(const f32x4*)(sG1 + j0 + 4);
    f32x4 g2a = *(const f32x4*)(sG2 + j0);
    f32x4 g2b = *(const f32x4*)(sG2 + j0 + 4);
    float wv0[8], wv1[8];
#pragma unroll
    for (int e = 0; e < 8; ++e) {
      float g1 = (e < 4) ? g1a[e] : g1b[e - 4];
      float g2 = (e < 4) ? g2a[e] : g2b[e - 4];
      float v0 = fmaxf(F10 * g1, F20 * g2);   // exp(lrelu(s+t)-m), branch-free
      float v1 = fmaxf(F11 * g1, F21 * g2);
      wv0[e] = ((by0 >> e) & 1u) ? v0 : 0.f;
      wv1[e] = ((by1 >> e) & 1u) ? v1 : 0.f;
    }
    union { unsigned u[4]; bf16x8 v; } pa0, pa1;
    pa0.u[0] = pk2(wv0[0], wv0[1]); pa0.u[1] = pk2(wv0[2], wv0[3]);
    pa0.u[2] = pk2(wv0[4], wv0[5]); pa0.u[3] = pk2(wv0[6], wv0[7]);
    pa1.u[0] = pk2(wv1[0], wv1[1]); pa1.u[1] = pk2(wv1[2], wv1[3]);
    pa1.u[2] = pk2(wv1[4], wv1[5]); pa1.u[3] = pk2(wv1[6], wv1[7]);
#pragma unroll
    for (int ft = 0; ft < 4; ++ft) {
      acc[0][ft] = __builtin_amdgcn_mfma_f32_16x16x32_bf16(pa0.v, curf[ft], acc[0][ft], 0, 0, 0);
      acc[1][ft] = __builtin_amdgcn_mfma_f32_16x16x32_bf16(pa1.v, curf[ft], acc[1][ft], 0, 0, 0);
    }
    accd[0] = __builtin_amdgcn_mfma_f32_16x16x32_bf16(pa0.v, ones, accd[0], 0, 0, 0);
    accd[1] = __builtin_amdgcn_mfma_f32_16x16x32_bf16(pa1.v, ones, accd[1], 0, 0, 0);
#pragma unroll
    for (int ft = 0; ft < 4; ++ft) curf[ft] = nxtf[ft];
  }
  __syncthreads();                     // all phase-1 LDS reads done; overlay safe
  if (jh > 0) {
    int p = jh - 1;
#pragma unroll
    for (int f = 0; f < 2; ++f) {
#pragma unroll
      for (int ft = 0; ft < 4; ++ft)
#pragma unroll
        for (int r = 0; r < 4; ++r)
          cmb[p][rt][f * 16 + 4 * g + r][ft * 16 + cl] = acc[f][ft][r];
      if (cl == 0) {
#pragma unroll
        for (int r = 0; r < 4; ++r) sden[p][rt][f * 16 + 4 * g + r] = accd[f][r];
      }
    }
  }
  __syncthreads();
  if (jh == 0) {
#pragma unroll
    for (int f = 0; f < 2; ++f) {
#pragma unroll
      for (int r = 0; r < 4; ++r) {
        int rloc32 = f * 16 + 4 * g + r;
        float dself = __shfl(accd[f][r], lane & 48);   // denom col 0 at cl==0
        float den = dself + sden[0][rt][rloc32] + sden[1][rt][rloc32] + sden[2][rt][rloc32];
        float inv = 1.f / den;
        int row = rowblk + rbase + rloc32;
        unsigned short* dst = hout + (size_t)(b * NN + row) * 256 + h * 64;
#pragma unroll
        for (int ft = 0; ft < 4; ++ft) {
          float v = acc[f][ft][r] + cmb[0][rt][rloc32][ft * 16 + cl] +
                    cmb[1][rt][rloc32][ft * 16 + cl] + cmb[2][rt][rloc32][ft * 16 + cl];
          v *= inv;
          v = v > 0.f ? v : (__expf(v) - 1.f);      // ELU
          dst[ft * 16 + cl] = f2bf1(v);             // bf16 (k3 rounds here anyway)
        }
      }
    }
  }
}

// ---------- k3: Wh2 = h @ W2^T via MFMA split-K; frag-layout store + scores ----
__global__ __launch_bounds__(256) void k3_proj2(
    const unsigned short* __restrict__ hin, const float* __restrict__ W2,
    const float* __restrict__ a2, unsigned short* __restrict__ wh2t,
    float* __restrict__ ssrc2, float* __restrict__ G1o, float* __restrict__ G2o) {
  __shared__ float cmb[4][16][33];
  int blk = blockIdx.x;                 // 512: 16 rows each
  int b = blk >> 7, rowbase = (blk & 127) << 4;
  int t = threadIdx.x, lane = t & 63, w = t >> 6;
  int cl = lane & 15, g = lane >> 4;
  int k0 = w * 64;                      // K split across 4 waves

  const unsigned short* hr = hin + (size_t)(b * NN + rowbase + cl) * 256 + k0 + 8 * g;
  bf16x8 af[2];
#pragma unroll
  for (int ks = 0; ks < 2; ++ks)
    af[ks] = *(const bf16x8*)(hr + ks * 32);       // bf16 direct A-fragment

  f32x4 zero = {0.f, 0.f, 0.f, 0.f};
  f32x4 acc[2] = {zero, zero};
#pragma unroll
  for (int ft = 0; ft < 2; ++ft) {
    const float* wr = W2 + (size_t)(ft * 16 + cl) * 256 + k0 + 8 * g;
#pragma unroll
    for (int ks = 0; ks < 2; ++ks) {
      bf16x8 bfr = cvt8(*(const f32x4*)(wr + ks * 32), *(const f32x4*)(wr + ks * 32 + 4));
      acc[ft] = __builtin_amdgcn_mfma_f32_16x16x32_bf16(af[ks], bfr, acc[ft], 0, 0, 0);
    }
  }
#pragma unroll
  for (int ft = 0; ft < 2; ++ft)
#pragma unroll
    for (int r = 0; r < 4; ++r)
      cmb[w][4 * g + r][ft * 16 + cl] = acc[ft][r];
  __syncthreads();

  int row = t >> 4, c0 = t & 15;
  float v0 = cmb[0][row][c0] + cmb[1][row][c0] + cmb[2][row][c0] + cmb[3][row][c0];
  float v1 = cmb[0][row][c0 + 16] + cmb[1][row][c0 + 16] + cmb[2][row][c0 + 16] + cmb[3][row][c0 + 16];
  float ps = v0 * a2[c0] + v1 * a2[c0 + 16];
  float pd = v0 * a2[32 + c0] + v1 * a2[32 + c0 + 16];
  ps += __shfl_xor(ps, 1); ps += __shfl_xor(ps, 2); ps += __shfl_xor(ps, 4); ps += __shfl_xor(ps, 8);
  pd += __shfl_xor(pd, 1); pd += __shfl_xor(pd, 2); pd += __shfl_xor(pd, 4); pd += __shfl_xor(pd, 8);
  if (c0 == 0) {
    int idx = b * NN + rowbase + row;
    ssrc2[idx] = ps;
    G1o[idx] = __expf(pd);
    G2o[idx] = __expf(0.2f * pd);
  }
  cmb[0][row][c0] = v0;
  cmb[0][row][c0 + 16] = v1;
  __syncthreads();
  // fragment-layout bf16 store: feat = col, nodes J = rowbase + 2*rg + {0,1}
  int col = t >> 3, rg = t & 7;
  unsigned pk = pk2(cmb[0][2 * rg][col], cmb[0][2 * rg + 1][col]);
  int kb2 = rowbase >> 5;
  int gd = ((rowbase >> 3) & 2) + (rg >> 2);
  size_t off = (size_t)(kb2 * 2 + (col >> 4)) * 512 + (col & 15) * 8 + gd * 128 + 2 * (rg & 3);
  *(unsigned*)(wh2t + (size_t)b * 32 * NN + off) = pk;
}

// ---------- k4: layer-2 attention. 512 blocks x 16 rows; 8 waves = 8 j-eighths
// doubles occupancy (was 256 blocks = 1 block/CU); 7-slab LDS overlay combine
__global__ __launch_bounds__(512) void k4_attn2(
    const unsigned short* __restrict__ wh2t, const float* __restrict__ ssrc2,
    const float* __restrict__ G1o, const float* __restrict__ G2o,
    const unsigned* __restrict__ mb, float* __restrict__ outp) {
  // phase 1: sdm[16][65] 4160 B | sG1 8 KB | sG2 8 KB = 20544 B
  // phase 2 (overlay): cmb[7][16][36] 16128 B + sden[7][16] 448 B = 16576 B
  __shared__ __align__(16) char smem[20608];
  __shared__ float swmax[8];
  unsigned (*sdm)[65] = (unsigned(*)[65])smem;
  float* sG1 = (float*)(smem + 4160);
  float* sG2 = (float*)(smem + 4160 + 8192);
  float (*cmb)[16][36] = (float(*)[16][36])smem;
  float (*sden)[16] = (float(*)[16])(smem + 16128);

  int bid = blockIdx.x;                // 512 = [tile(7 hi)][b(2 lo)]
  int b = bid & 3, tile = bid >> 2;
  int rowblk = tile << 4;              // 16 rows per block
  int t = threadIdx.x, lane = t & 63, w = t >> 6;  // w = j-eighth
  int cl = lane & 15, g = lane >> 4, g8 = g * 8;

  { // stage 16 rows x 64 mask words (2 per thread)
    int row = t >> 5, c = (t & 31) * 2;
    uint2 v = *(const uint2*)(mb + (size_t)(b * NN + rowblk + row) * NW + c);
    sdm[row][c + 0] = v.x; sdm[row][c + 1] = v.y;
  }
  { // stage G + block-local max of G1
    f32x4 gv = ((const f32x4*)(G1o + (size_t)b * NN))[t];
    ((f32x4*)sG1)[t] = gv;
    ((f32x4*)sG2)[t] = ((const f32x4*)(G2o + (size_t)b * NN))[t];
    float gmx = fmaxf(fmaxf(gv[0], gv[1]), fmaxf(gv[2], gv[3]));
    gmx = fmaxf(gmx, __shfl_xor(gmx, 1));  gmx = fmaxf(gmx, __shfl_xor(gmx, 2));
    gmx = fmaxf(gmx, __shfl_xor(gmx, 4));  gmx = fmaxf(gmx, __shfl_xor(gmx, 8));
    gmx = fmaxf(gmx, __shfl_xor(gmx, 16)); gmx = fmaxf(gmx, __shfl_xor(gmx, 32));
    if (lane == 0) swmax[w] = gmx;
  }
  float s = ssrc2[b * NN + rowblk + cl];
  __syncthreads();
  float mxv = fmaxf(fmaxf(fmaxf(swmax[0], swmax[1]), fmaxf(swmax[2], swmax[3])),
                    fmaxf(fmaxf(swmax[4], swmax[5]), fmaxf(swmax[6], swmax[7])));
  float logMx = __logf(mxv);
  float m = lrelu(s + logMx);
  float F1 = __expf(s - m), F2 = __expf(0.2f * s - m);

  short onev = (cl == 0) ? (short)0x3F80 : (short)0;
  bf16x8 ones = {onev, onev, onev, onev, onev, onev, onev, onev};
  f32x4 zero = {0.f, 0.f, 0.f, 0.f};
  f32x4 acc[2] = {zero, zero};
  f32x4 acc1 = zero;
  const unsigned short* fbase = wh2t + (size_t)b * 32 * NN + lane * 8;
  int kb0 = w * 8;

  bf16x8 curf[2], nxtf[2];
#pragma unroll
  for (int ft = 0; ft < 2; ++ft)
    curf[ft] = *(const bf16x8*)(fbase + (size_t)(kb0 * 2 + ft) * 512);

  for (int i = 0; i < 8; ++i) {
    int kb = kb0 + i;
    if (i < 7) {
#pragma unroll
      for (int ft = 0; ft < 2; ++ft)
        nxtf[ft] = *(const bf16x8*)(fbase + (size_t)((kb + 1) * 2 + ft) * 512);
    }
    unsigned by = (sdm[cl][kb] >> g8) & 0xFFu;
    int j0 = kb * 32 + g8;
    f32x4 g1a = *(const f32x4*)(sG1 + j0);
    f32x4 g1b = *(const f32x4*)(sG1 + j0 + 4);
    f32x4 g2a = *(const f32x4*)(sG2 + j0);
    f32x4 g2b = *(const f32x4*)(sG2 + j0 + 4);
    float wv[8];
#pragma unroll
    for (int e = 0; e < 8; ++e) {
      float g1 = (e < 4) ? g1a[e] : g1b[e - 4];
      float g2 = (e < 4) ? g2a[e] : g2b[e - 4];
      float v = fmaxf(F1 * g1, F2 * g2);
      wv[e] = ((by >> e) & 1u) ? v : 0.f;
    }
    union { unsigned u[4]; bf16x8 v; } pa;
    pa.u[0] = pk2(wv[0], wv[1]); pa.u[1] = pk2(wv[2], wv[3]);
    pa.u[2] = pk2(wv[4], wv[5]); pa.u[3] = pk2(wv[6], wv[7]);
#pragma unroll
    for (int ft = 0; ft < 2; ++ft)
      acc[ft] = __builtin_amdgcn_mfma_f32_16x16x32_bf16(pa.v, curf[ft], acc[ft], 0, 0, 0);
    acc1 = __builtin_amdgcn_mfma_f32_16x16x32_bf16(pa.v, ones, acc1, 0, 0, 0);
#pragma unroll
    for (int ft = 0; ft < 2; ++ft) curf[ft] = nxtf[ft];
  }
  __syncthreads();                     // all phase-1 LDS reads done; overlay safe
  if (w > 0) {
    int p = w - 1;
#pragma unroll
    for (int ft = 0; ft < 2; ++ft)
#pragma unroll
      for (int r = 0; r < 4; ++r)
        cmb[p][4 * g + r][ft * 16 + cl] = acc[ft][r];
    if (cl == 0) {
#pragma unroll
      for (int r = 0; r < 4; ++r) sden[p][4 * g + r] = acc1[r];
    }
  }
  __syncthreads();
  if (w == 0) {
#pragma unroll
    for (int r = 0; r < 4; ++r) {
      int rowm = 4 * g + r;
      float dself = __shfl(acc1[r], lane & 48);
      float den = dself;
#pragma unroll
      for (int p = 0; p < 7; ++p) den += sden[p][rowm];
      float inv = 1.f / den;
      float* dst = outp + (size_t)(b * NN + rowblk + rowm) * 32;
#pragma unroll
      for (int ft = 0; ft < 2; ++ft) {
        float v = acc[ft][r];
#pragma unroll
        for (int p = 0; p < 7; ++p) v += cmb[p][rowm][ft * 16 + cl];
        dst[ft * 16 + cl] = v * inv;
      }
    }
  }
}

extern "C" void kernel_launch(void* const* d_in, const int* in_sizes, int n_in,
                              void* d_out, int out_size, void* d_ws, size_t ws_size,
                              hipStream_t stream) {
  (void)in_sizes; (void)n_in; (void)out_size; (void)ws_size;
  const float* x   = (const float*)d_in[0];
  const int*   adj = (const int*)d_in[1];
  const float* W1  = (const float*)d_in[2];
  const float* a1  = (const float*)d_in[3];
  const float* W2  = (const float*)d_in[4];
  const float* a2  = (const float*)d_in[5];
  float* outp = (float*)d_out;
  char* ws = (char*)d_ws;

  unsigned*       mbits = (unsigned*)(ws);                                   // 2 MB
  unsigned short* wht1  = (unsigned short*)(ws + (size_t)(2u << 20));        // 4 MB
  float*          ssrc1 = (float*)(ws + (size_t)(6u << 20));                 // 128 KB
  float*          G1g   = (float*)(ws + (size_t)(6u << 20) + (128u << 10));  // 128 KB
  float*          G2g   = (float*)(ws + (size_t)(6u << 20) + (256u << 10));  // 128 KB
  unsigned short* hbuf  = (unsigned short*)(ws + (size_t)(6u << 20) + (512u << 10)); // 4 MB bf16
  unsigned short* wh2t  = (unsigned short*)(ws + (size_t)(14u << 20) + (512u << 10)); // 512 KB
  float*          ssrc2 = (float*)(ws + (size_t)(15u << 20));                // 32 KB
  float*          G1o   = (float*)(ws + (size_t)(15u << 20) + (32u << 10));  // 32 KB
  float*          G2o   = (float*)(ws + (size_t)(15u << 20) + (64u << 10));  // 32 KB

  kA      <<<2560, 256, 0, stream>>>(adj, mbits, x, W1, a1, wht1, ssrc1, G1g, G2g);
  k2_attn1<<<512,  512, 0, stream>>>(wht1, ssrc1, G1g, G2g, mbits, hbuf);
  k3_proj2<<<512,  256, 0, stream>>>(hbuf, W2, a2, wh2t, ssrc2, G1o, G2o);
  k4_attn2<<<512,  512, 0, stream>>>(wh2t, ssrc2, G1o, G2o, mbits, outp);
}